// Round 4
// baseline (770.963 us; speedup 1.0000x reference)
//
#include <hip/hip_runtime.h>
#include <hip/hip_fp16.h>

// EMD approx-match (auction) + match_cost, fully fused, ONE normal launch.
// R18: R17 (715us, VALUBusy 32%) carries ~486us stall vs dispatch's ~127us.
// Evidence: WRITE_SIZE 79MB == atomic_count*4B -> every t1 atomicAdd writes
// through to HBM; and all 128 blocks issue atomics in IDENTICAL index order
// (one 64B line per wave-iteration) -> up to 128-deep per-line RMW queues
// whose completion tail each block's vmcnt(0) drain eats. Plus the barrier
// polled with a plain agent LOAD, which can be served stale by the
// non-coherent XCD L2 (eviction-bound release latency). Fixes this round:
// (a) poll with __hip_atomic_fetch_add(c,0) (RMW executes at the coherent
//     point, immune to stale L2) + s_sleep(8);
// (b) per-block stagger of sweep2 atomic order (itp = (it + bid*5) & MASK):
//     concurrent writers per line drop ~128 -> ~4. Zero memory cost.
// Everything else identical to R17.

#define BATCH 8
#define NPTS 2048
#define MPTS 2048
#define BLOCK 256
#define ROWS 16
#define BLOCKS_PER_BATCH 128
#define NSYNC 11
#define LOG2E 1.44269504088896340736f

__device__ __forceinline__ float fast_exp2(float x) {
  return __builtin_amdgcn_exp2f(x);     // v_exp_f32
}
__device__ __forceinline__ float fast_sqrt(float a) {
  return __builtin_amdgcn_sqrtf(a);     // v_sqrt_f32
}
__device__ __forceinline__ float packh2(float c, float r) {
  __half2 h = __halves2half2(__float2half_rn(c), __float2half_rn(r));
  return __builtin_bit_cast(float, h);
}

// ---- agent-scope coherent access helpers (bypass non-coherent XCD L2) ----
__device__ __forceinline__ float cohLoad(const float* p) {
  return __hip_atomic_load((float*)p, __ATOMIC_RELAXED,
                           __HIP_MEMORY_SCOPE_AGENT);
}
__device__ __forceinline__ void cohStore(float* p, float v) {
  __hip_atomic_store(p, v, __ATOMIC_RELAXED, __HIP_MEMORY_SCOPE_AGENT);
}
__device__ __forceinline__ float4 cohLoad4(const float4* p) {
  const float* f = (const float*)p;
  return make_float4(cohLoad(f), cohLoad(f + 1), cohLoad(f + 2),
                     cohLoad(f + 3));
}
__device__ __forceinline__ void cohStore4(float4* p, float4 v) {
  float* f = (float*)p;
  cohStore(f, v.x); cohStore(f + 1, v.y);
  cohStore(f + 2, v.z); cohStore(f + 3, v.w);
}

// Per-batch grid barrier. Monotonic round-up target: correct across graph
// replays. __syncthreads before arrive drains vmcnt(0) -> this block's
// coherent writes/atomics have completed at the coherent point. POLL IS AN
// ATOMIC RMW (fetch_add 0): forced to execute at the coherent point every
// iteration -- a plain load can be served stale by the local XCD L2.
__device__ __forceinline__ void batch_barrier(unsigned* c) {
  __syncthreads();
  if (threadIdx.x == 0) {
    unsigned old = __hip_atomic_fetch_add(c, 1u, __ATOMIC_RELAXED,
                                          __HIP_MEMORY_SCOPE_AGENT);
    unsigned target = (old / BLOCKS_PER_BATCH + 1u) * BLOCKS_PER_BATCH;
    int guard = 0;
    while (__hip_atomic_fetch_add(c, 0u, __ATOMIC_RELAXED,
                                  __HIP_MEMORY_SCOPE_AGENT) < target) {
      __builtin_amdgcn_s_sleep(8);
      if (++guard > (1 << 20)) break;
    }
  }
  asm volatile("" ::: "memory");
  __syncthreads();
}

// Load 8 consecutive points (r0 multiple of 8) as 6 float4s (raw).
__device__ __forceinline__ void load8(const float4* q, int r0,
                                      float* x, float* y, float* z) {
  int b4 = (r0 >> 2) * 3;
  float4 q0 = q[b4], q1 = q[b4 + 1], q2 = q[b4 + 2];
  float4 q3 = q[b4 + 3], q4 = q[b4 + 4], q5 = q[b4 + 5];
  x[0] = q0.x; y[0] = q0.y; z[0] = q0.z;
  x[1] = q0.w; y[1] = q1.x; z[1] = q1.y;
  x[2] = q1.z; y[2] = q1.w; z[2] = q2.x;
  x[3] = q2.y; y[3] = q2.z; z[3] = q2.w;
  x[4] = q3.x; y[4] = q3.y; z[4] = q3.z;
  x[5] = q3.w; y[5] = q4.x; z[5] = q4.y;
  x[6] = q4.z; y[6] = q4.w; z[6] = q5.x;
  x[7] = q5.y; y[7] = q5.z; z[7] = q5.w;
}

__global__ __launch_bounds__(BLOCK, 4) void emd_fused_kernel(
    const float* __restrict__ xyz1, const float* __restrict__ xyz2,
    float* __restrict__ out, float* __restrict__ t1b,
    float* __restrict__ rrA, float* __restrict__ rrB,
    float* __restrict__ t9, unsigned* __restrict__ ctr) {
  __shared__ float4 sP[MPTS];           // raw x2,y2,z2; w = per-level payload
  __shared__ float sRedS[ROWS * 4];
  __shared__ float sRedC[ROWS * 4];
  __shared__ float sRedR[ROWS * 4];
  __shared__ float sCost[ROWS];
  __shared__ float sRowScale[ROWS];     // persistent across levels
  __shared__ float sRemainL[ROWS];      // persistent across levels
  __shared__ float sRn[4];              // LAST-level sum(rn) partials

  const int tid = threadIdx.x;
  const int bid = blockIdx.x;
  const int b = bid >> 7;
  const int t0 = (bid & 127) * ROWS;
  const bool desig = (bid & 127) == 0;
  const int wave = tid >> 6, lane = tid & 63;
  const size_t bM = (size_t)b * MPTS;
  unsigned* cb = ctr + b;               // per-batch counters, stride BATCH
  const int stag = (bid * 5) & 31;      // sweep2 atomic-order stagger

  float* cur = t1b + bM;
  float* nxt = t1b + (size_t)(BATCH * MPTS) + bM;
  float* zer = t1b + (size_t)(2 * BATCH * MPTS) + bM;
  float* rin = rrA + bM;
  float* rou = rrB + bM;

  const float4* q1 = (const float4*)(xyz1 + (size_t)b * NPTS * 3);
  const float4* q2 = (const float4*)(xyz2 + bM * 3);

  // ---- init: stage raw coords once; zero t1 buf0/buf1, out[b], t9[b] ----
  {
    float4* z0 = (float4*)cur;
    float4* z1 = (float4*)nxt;
    const float4 zz = make_float4(0.f, 0.f, 0.f, 0.f);
    for (int g = tid; g < MPTS / 4; g += BLOCK) {
      float4 a = q2[3 * g], bb = q2[3 * g + 1], c = q2[3 * g + 2];
      sP[4 * g + 0] = make_float4(a.x, a.y, a.z, 0.f);
      sP[4 * g + 1] = make_float4(a.w, bb.x, bb.y, 0.f);
      sP[4 * g + 2] = make_float4(bb.z, bb.w, c.x, 0.f);
      sP[4 * g + 3] = make_float4(c.y, c.z, c.w, 0.f);
      if (desig) { cohStore4(z0 + g, zz); cohStore4(z1 + g, zz); }
    }
    if (desig && tid == 0) { cohStore(out + b, 0.f); cohStore(t9 + b, 0.f); }
  }
  __syncthreads();

  // ---- A0: rowscale_0, then t1_0 accumulation ----
  const float nc0 = -16384.0f * LOG2E;
  {
    const int ph = lane >> 1, rg = lane & 1;
    float x1a[8], y1a[8], z1a[8], acc[8];
    load8(q1, t0 + rg * 8, x1a, y1a, z1a);
#pragma unroll
    for (int j = 0; j < 8; ++j) acc[j] = 0.f;
    const int mb = wave * 512 + ph;
#pragma unroll 2
    for (int it = 0; it < 16; ++it) {
      float4 v = sP[mb + it * 32];
#pragma unroll
      for (int j = 0; j < 8; ++j) {
        float dx = x1a[j] - v.x, dy = y1a[j] - v.y, dz = z1a[j] - v.z;
        float d2 = __builtin_fmaf(dx, dx, __builtin_fmaf(dy, dy, dz * dz));
        acc[j] += fast_exp2(nc0 * d2);
      }
    }
#pragma unroll
    for (int j = 0; j < 8; ++j) {
      acc[j] += __shfl_xor(acc[j], 2, 64);
      acc[j] += __shfl_xor(acc[j], 4, 64);
      acc[j] += __shfl_xor(acc[j], 8, 64);
      acc[j] += __shfl_xor(acc[j], 16, 64);
      acc[j] += __shfl_xor(acc[j], 32, 64);
    }
    if (lane < 2) {
#pragma unroll
      for (int j = 0; j < 8; ++j) sRedS[(rg * 8 + j) * 4 + wave] = acc[j];
    }
    __syncthreads();
    if (tid < ROWS) {
      float s = sRedS[tid * 4] + sRedS[tid * 4 + 1] + sRedS[tid * 4 + 2] +
                sRedS[tid * 4 + 3];
      sRowScale[tid] = 1.0f / (s + 1e-9f);
    }
    // barrier 0: t1 buf zeroes + out/t9 zeroes at coherent point before any
    // atomics; also the block barrier for sRowScale.
    batch_barrier(cb + 0 * BATCH);
    float rsn[8];
#pragma unroll
    for (int j = 0; j < 8; ++j) rsn[j] = sRowScale[rg * 8 + j];
#pragma unroll 2
    for (int it = 0; it < 16; ++it) {
      int itp = (it + stag) & 15;       // staggered atomic order
      int idx = mb + itp * 32;
      float4 v = sP[idx];
      float part = 0.f;
#pragma unroll
      for (int j = 0; j < 8; ++j) {
        float dx = x1a[j] - v.x, dy = y1a[j] - v.y, dz = z1a[j] - v.z;
        float d2 = __builtin_fmaf(dx, dx, __builtin_fmaf(dy, dy, dz * dz));
        part = __builtin_fmaf(fast_exp2(nc0 * d2), rsn[j], part);
      }
      part += __shfl_xor(part, 1, 64);
      if (rg == 0) atomicAdd(cur + idx, part);
    }
  }
  // barrier 1: t1_0 accumulation complete before level-0 staging reads it.
  batch_barrier(cb + 1 * BATCH);

  // ---- persistent CA row fragment (raw coords) ----
  float x1[4], y1[4], z1[4];
  {
    int b4 = ((t0 + (lane & 3) * 4) >> 2) * 3;
    float4 a = q1[b4], bb = q1[b4 + 1], c = q1[b4 + 2];
    x1[0] = a.x;  y1[0] = a.y;  z1[0] = a.z;
    x1[1] = a.w;  y1[1] = bb.x; z1[1] = bb.y;
    x1[2] = bb.z; y1[2] = bb.w; z1[2] = c.x;
    x1[3] = c.y;  y1[3] = c.z;  z1[3] = c.w;
  }
  const int phc = lane >> 2, rgc = lane & 3;
  const int mbc = wave * 512 + phc;

  float nc2 = -4096.0f * LOG2E;   // levels[l+1]*LOG2E; exact /4 per level
  for (int l = 0; l < 9; ++l) {
    const bool LAST = (l == 8);
    float rnsum = 0.f;
    {
      const float4* t14 = (const float4*)cur;
      const float4* rr4 = (const float4*)rin;
      float4* ro4 = (float4*)rou;
      float4* z4 = (float4*)zer;
      const float4 zz = make_float4(0.f, 0.f, 0.f, 0.f);
      for (int g = tid; g < MPTS / 4; g += BLOCK) {
        float4 t1v = cohLoad4(t14 + g);
        float4 rrv = (l == 0) ? make_float4(1.f, 1.f, 1.f, 1.f)
                              : cohLoad4(rr4 + g);
        float rrc[4] = {rrv.x, rrv.y, rrv.z, rrv.w};
        float t1c[4] = {t1v.x, t1v.y, t1v.z, t1v.w};
        float cc[4], rn[4];
#pragma unroll
        for (int i = 0; i < 4; ++i) {
          float colsum = rrc[i] * t1c[i];
          float cs = fminf(rrc[i] / (colsum + 1e-9f), 1.0f);
          cc[i] = rrc[i] * cs;
          rn[i] = fmaxf(rrc[i] - colsum * cs, 0.f);
        }
        rnsum += rn[0] + rn[1] + rn[2] + rn[3];
        sP[4 * g + 0].w = packh2(cc[0], rn[0]);
        sP[4 * g + 1].w = packh2(cc[1], rn[1]);
        sP[4 * g + 2].w = packh2(cc[2], rn[2]);
        sP[4 * g + 3].w = packh2(cc[3], rn[3]);
        if (desig) {
          cohStore4(ro4 + g, make_float4(rn[0], rn[1], rn[2], rn[3]));
          if (!LAST) cohStore4(z4 + g, zz);
        }
      }
      if (LAST) {   // R at last level = sum_m rn (e2 == 1)
        rnsum += __shfl_xor(rnsum, 1, 64);
        rnsum += __shfl_xor(rnsum, 2, 64);
        rnsum += __shfl_xor(rnsum, 4, 64);
        rnsum += __shfl_xor(rnsum, 8, 64);
        rnsum += __shfl_xor(rnsum, 16, 64);
        rnsum += __shfl_xor(rnsum, 32, 64);
        if (lane == 0) sRn[wave] = rnsum;
      }
    }
    __syncthreads();
    float accS[4] = {0.f, 0.f, 0.f, 0.f};
    float accC[4] = {0.f, 0.f, 0.f, 0.f};
    float accR[4] = {0.f, 0.f, 0.f, 0.f};
#pragma unroll 4
    for (int it = 0; it < 32; ++it) {
      float4 v = sP[mbc + it * 16];
      __half2 h = __builtin_bit_cast(__half2, v.w);
      float cc = __low2float(h);
      float rr = __high2float(h);
#pragma unroll
      for (int j = 0; j < 4; ++j) {
        float dx = x1[j] - v.x, dy = y1[j] - v.y, dz = z1[j] - v.z;
        float d2 = __builtin_fmaf(dx, dx, __builtin_fmaf(dy, dy, dz * dz));
        float sq = fast_sqrt(d2);
        float e2 = fast_exp2(nc2 * d2);
        float e2s = e2 * e2;
        float e1 = e2s * e2s;   // exp(levels[l]*d2); at LAST -> exp(-0.25 d2)
        float t = e1 * cc;
        accS[j] += t;
        accC[j] = __builtin_fmaf(t, sq, accC[j]);
        accR[j] = __builtin_fmaf(e2, rr, accR[j]);
      }
    }
#pragma unroll
    for (int j = 0; j < 4; ++j) {
      accS[j] += __shfl_xor(accS[j], 4, 64);
      accS[j] += __shfl_xor(accS[j], 8, 64);
      accS[j] += __shfl_xor(accS[j], 16, 64);
      accS[j] += __shfl_xor(accS[j], 32, 64);
      accC[j] += __shfl_xor(accC[j], 4, 64);
      accC[j] += __shfl_xor(accC[j], 8, 64);
      accC[j] += __shfl_xor(accC[j], 16, 64);
      accC[j] += __shfl_xor(accC[j], 32, 64);
      accR[j] += __shfl_xor(accR[j], 4, 64);
      accR[j] += __shfl_xor(accR[j], 8, 64);
      accR[j] += __shfl_xor(accR[j], 16, 64);
      accR[j] += __shfl_xor(accR[j], 32, 64);
    }
    if (lane < 4) {
#pragma unroll
      for (int j = 0; j < 4; ++j) {
        sRedS[(rgc * 4 + j) * 4 + wave] = accS[j];
        sRedC[(rgc * 4 + j) * 4 + wave] = accC[j];
        sRedR[(rgc * 4 + j) * 4 + wave] = accR[j];
      }
    }
    __syncthreads();
    if (tid < ROWS) {
      float S2 = sRedS[tid * 4] + sRedS[tid * 4 + 1] + sRedS[tid * 4 + 2] +
                 sRedS[tid * 4 + 3];
      float C = sRedC[tid * 4] + sRedC[tid * 4 + 1] + sRedC[tid * 4 + 2] +
                sRedC[tid * 4 + 3];
      float R = sRedR[tid * 4] + sRedR[tid * 4 + 1] + sRedR[tid * 4 + 2] +
                sRedR[tid * 4 + 3];
      if (LAST) R = sRn[0] + sRn[1] + sRn[2] + sRn[3];
      float rs = sRowScale[tid];
      float rl = (l == 0) ? 1.0f : sRemainL[tid];
      float rlN = fmaxf(rl - rs * S2, 0.f);
      sRemainL[tid] = rlN;
      sRowScale[tid] = rlN / (R + 1e-9f);
      sCost[tid] = rs * C;
    }
    __syncthreads();
    if (tid == 0) {
      float t = 0.f;
#pragma unroll
      for (int i = 0; i < ROWS; ++i) t += sCost[i];
      atomicAdd(out + b, t);
      if (LAST) {
        float r = 0.f;
#pragma unroll
        for (int i = 0; i < ROWS; ++i) r += sRowScale[i];
        atomicAdd(t9 + b, r);
      }
    }
    if (!LAST) {
      float rsn[4];
#pragma unroll
      for (int j = 0; j < 4; ++j) rsn[j] = sRowScale[rgc * 4 + j];
#pragma unroll 4
      for (int it = 0; it < 32; ++it) {
        int itp = (it + stag) & 31;     // staggered atomic order
        int idx = mbc + itp * 16;
        float4 v = sP[idx];
        float part = 0.f;
#pragma unroll
        for (int j = 0; j < 4; ++j) {
          float dx = x1[j] - v.x, dy = y1[j] - v.y, dz = z1[j] - v.z;
          float d2 = __builtin_fmaf(dx, dx, __builtin_fmaf(dy, dy, dz * dz));
          part = __builtin_fmaf(fast_exp2(nc2 * d2), rsn[j], part);
        }
        part += __shfl_xor(part, 1, 64);
        part += __shfl_xor(part, 2, 64);
        if (rgc == 0) atomicAdd(nxt + idx, part);
      }
    }
    // barrier 2+l: t1_{l+1} accumulation + rr_{l+1} stores complete.
    batch_barrier(cb + (2 + l) * BATCH);
    if (!LAST) {
      float* tp = cur; cur = nxt; nxt = zer; zer = tp;
      float* tr = rin; rin = rou; rou = tr;
      nc2 *= 0.25f;
    }
  }

  // ---- C9 (lvl=0): t1 scalar = t9[b]; cost with unscaled coords ----
  {
    const float t1 = cohLoad(t9 + b);
    const float4* rr4 = (const float4*)rou;   // rr_9 (no rotate at LAST)
    for (int g = tid; g < MPTS / 4; g += BLOCK) {
      float4 rr = cohLoad4(rr4 + g);
      sP[4 * g + 0].w = rr.x * fminf(rr.x / (__builtin_fmaf(rr.x, t1, 1e-9f)), 1.0f);
      sP[4 * g + 1].w = rr.y * fminf(rr.y / (__builtin_fmaf(rr.y, t1, 1e-9f)), 1.0f);
      sP[4 * g + 2].w = rr.z * fminf(rr.z / (__builtin_fmaf(rr.z, t1, 1e-9f)), 1.0f);
      sP[4 * g + 3].w = rr.w * fminf(rr.w / (__builtin_fmaf(rr.w, t1, 1e-9f)), 1.0f);
    }
    __syncthreads();
    const int ph = lane >> 1, rg = lane & 1;
    float x1a[8], y1a[8], z1a[8], acc[8];
    load8(q1, t0 + rg * 8, x1a, y1a, z1a);
#pragma unroll
    for (int j = 0; j < 8; ++j) acc[j] = 0.f;
    const int mb = wave * 512 + ph;
#pragma unroll 2
    for (int it = 0; it < 16; ++it) {
      float4 v = sP[mb + it * 32];
#pragma unroll
      for (int j = 0; j < 8; ++j) {
        float dx = x1a[j] - v.x, dy = y1a[j] - v.y, dz = z1a[j] - v.z;
        float d2 = __builtin_fmaf(dx, dx, __builtin_fmaf(dy, dy, dz * dz));
        acc[j] = __builtin_fmaf(fast_sqrt(d2), v.w, acc[j]);
      }
    }
#pragma unroll
    for (int j = 0; j < 8; ++j) {
      acc[j] += __shfl_xor(acc[j], 2, 64);
      acc[j] += __shfl_xor(acc[j], 4, 64);
      acc[j] += __shfl_xor(acc[j], 8, 64);
      acc[j] += __shfl_xor(acc[j], 16, 64);
      acc[j] += __shfl_xor(acc[j], 32, 64);
    }
    if (lane < 2) {
#pragma unroll
      for (int j = 0; j < 8; ++j) sRedS[(rg * 8 + j) * 4 + wave] = acc[j];
    }
    __syncthreads();
    if (tid < ROWS) {
      float C = sRedS[tid * 4] + sRedS[tid * 4 + 1] + sRedS[tid * 4 + 2] +
                sRedS[tid * 4 + 3];
      sCost[tid] = sRowScale[tid] * C;
    }
    __syncthreads();
    if (tid == 0) {
      float t = 0.f;
#pragma unroll
      for (int i = 0; i < ROWS; ++i) t += sCost[i];
      atomicAdd(out + b, t);
    }
  }
}

// ---------------------------------------------------------------------------
extern "C" void kernel_launch(void* const* d_in, const int* in_sizes, int n_in,
                              void* d_out, int out_size, void* d_ws, size_t ws_size,
                              hipStream_t stream) {
  const float* xyz1 = (const float*)d_in[0];
  const float* xyz2 = (const float*)d_in[1];
  float* out = (float*)d_out;
  float* ws = (float*)d_ws;

  const int BM = BATCH * MPTS;
  float* rrA = ws;                       // BM
  float* rrB = ws + BM;                  // BM
  float* t1b = ws + 2 * BM;              // 3*BM (triple buffer)
  float* t9  = ws + 5 * BM;              // BATCH (pad to 16)
  unsigned* ctr = (unsigned*)(ws + 5 * BM + 16);  // NSYNC*BATCH counters

  // zero barrier counters (keeps them multiples of 128 across graph replays)
  hipMemsetAsync(ctr, 0, NSYNC * BATCH * sizeof(unsigned), stream);

  void* args[] = {(void*)&xyz1, (void*)&xyz2, (void*)&out, (void*)&t1b,
                  (void*)&rrA, (void*)&rrB, (void*)&t9, (void*)&ctr};
  hipLaunchKernel((const void*)emd_fused_kernel,
                  dim3(BATCH * (NPTS / ROWS)), dim3(BLOCK), args, 0, stream);
}

// Round 5
// 451.487 us; speedup vs baseline: 1.7076x; 1.7076x over previous
//
#include <hip/hip_runtime.h>
#include <hip/hip_fp16.h>

// EMD approx-match (auction) + match_cost, fully fused, ONE normal launch.
// R19: R18's nulls localized the stall to SAME-CACHE-LINE RMW chains at the
// coherent point (~44ns/serialized RMW): (1) out[0..7] is one 64B line
// receiving 1024 atomicAdds PER LEVEL (all blocks, all batches) ~= 45us/level
// -- the entire excess stall; (2) barrier counters for all 8 batches share a
// line (stride 4B), making each "per-batch" barrier a 1024-deep chain.
// Fixes: (a) per-block register costAcc across all levels+C9, ONE atomicAdd
// per block into 64B-padded per-batch outAcc, final barrier, desig block
// plain-stores out[b]; (b) t9 and each (sync,batch) counter get their own
// 64B line; (c) poll reverted to plain agent load (R18's RMW poll fed the
// arrival chain, -60us), stagger dropped (null => t1 atomics are cheap:
// 128-deep distinct-dword chains, overlapped with compute).

#define BATCH 8
#define NPTS 2048
#define MPTS 2048
#define BLOCK 256
#define ROWS 16
#define BLOCKS_PER_BATCH 128
#define NSYNC 12
#define PAD 16                     // dwords per 64B line
#define LOG2E 1.44269504088896340736f

__device__ __forceinline__ float fast_exp2(float x) {
  return __builtin_amdgcn_exp2f(x);     // v_exp_f32
}
__device__ __forceinline__ float fast_sqrt(float a) {
  return __builtin_amdgcn_sqrtf(a);     // v_sqrt_f32
}
__device__ __forceinline__ float packh2(float c, float r) {
  __half2 h = __halves2half2(__float2half_rn(c), __float2half_rn(r));
  return __builtin_bit_cast(float, h);
}

// ---- agent-scope coherent access helpers (bypass non-coherent XCD L2) ----
__device__ __forceinline__ float cohLoad(const float* p) {
  return __hip_atomic_load((float*)p, __ATOMIC_RELAXED,
                           __HIP_MEMORY_SCOPE_AGENT);
}
__device__ __forceinline__ void cohStore(float* p, float v) {
  __hip_atomic_store(p, v, __ATOMIC_RELAXED, __HIP_MEMORY_SCOPE_AGENT);
}
__device__ __forceinline__ float4 cohLoad4(const float4* p) {
  const float* f = (const float*)p;
  return make_float4(cohLoad(f), cohLoad(f + 1), cohLoad(f + 2),
                     cohLoad(f + 3));
}
__device__ __forceinline__ void cohStore4(float4* p, float4 v) {
  float* f = (float*)p;
  cohStore(f, v.x); cohStore(f + 1, v.y);
  cohStore(f + 2, v.z); cohStore(f + 3, v.w);
}

// Per-batch grid barrier; counter must own its own 64B line. Monotonic
// round-up target: replay-safe. __syncthreads before arrive drains vmcnt(0)
// -> this block's coherent writes/atomics are complete at the coherent point.
// Poll is a PLAIN agent load (R18 showed RMW-poll feeds the arrival chain).
__device__ __forceinline__ void batch_barrier(unsigned* c) {
  __syncthreads();
  if (threadIdx.x == 0) {
    unsigned old = __hip_atomic_fetch_add(c, 1u, __ATOMIC_RELAXED,
                                          __HIP_MEMORY_SCOPE_AGENT);
    unsigned target = (old / BLOCKS_PER_BATCH + 1u) * BLOCKS_PER_BATCH;
    int guard = 0;
    while (__hip_atomic_load(c, __ATOMIC_RELAXED,
                             __HIP_MEMORY_SCOPE_AGENT) < target) {
      __builtin_amdgcn_s_sleep(2);
      if (++guard > (1 << 22)) break;
    }
  }
  asm volatile("" ::: "memory");
  __syncthreads();
}

// Load 8 consecutive points (r0 multiple of 8) as 6 float4s (raw).
__device__ __forceinline__ void load8(const float4* q, int r0,
                                      float* x, float* y, float* z) {
  int b4 = (r0 >> 2) * 3;
  float4 q0 = q[b4], q1 = q[b4 + 1], q2 = q[b4 + 2];
  float4 q3 = q[b4 + 3], q4 = q[b4 + 4], q5 = q[b4 + 5];
  x[0] = q0.x; y[0] = q0.y; z[0] = q0.z;
  x[1] = q0.w; y[1] = q1.x; z[1] = q1.y;
  x[2] = q1.z; y[2] = q1.w; z[2] = q2.x;
  x[3] = q2.y; y[3] = q2.z; z[3] = q2.w;
  x[4] = q3.x; y[4] = q3.y; z[4] = q3.z;
  x[5] = q3.w; y[5] = q4.x; z[5] = q4.y;
  x[6] = q4.z; y[6] = q4.w; z[6] = q5.x;
  x[7] = q5.y; y[7] = q5.z; z[7] = q5.w;
}

__global__ __launch_bounds__(BLOCK, 4) void emd_fused_kernel(
    const float* __restrict__ xyz1, const float* __restrict__ xyz2,
    float* __restrict__ out, float* __restrict__ t1b,
    float* __restrict__ rrA, float* __restrict__ rrB,
    float* __restrict__ t9, float* __restrict__ outAcc,
    unsigned* __restrict__ ctr) {
  __shared__ float4 sP[MPTS];           // raw x2,y2,z2; w = per-level payload
  __shared__ float sRedS[ROWS * 4];
  __shared__ float sRedC[ROWS * 4];
  __shared__ float sRedR[ROWS * 4];
  __shared__ float sCost[ROWS];
  __shared__ float sRowScale[ROWS];     // persistent across levels
  __shared__ float sRemainL[ROWS];      // persistent across levels
  __shared__ float sRn[4];              // LAST-level sum(rn) partials

  const int tid = threadIdx.x;
  const int bid = blockIdx.x;
  const int b = bid >> 7;
  const int t0 = (bid & 127) * ROWS;
  const bool desig = (bid & 127) == 0;
  const int wave = tid >> 6, lane = tid & 63;
  const size_t bM = (size_t)b * MPTS;
  float costAcc = 0.f;                  // per-block deferred cost (tid0 only)

  float* cur = t1b + bM;
  float* nxt = t1b + (size_t)(BATCH * MPTS) + bM;
  float* zer = t1b + (size_t)(2 * BATCH * MPTS) + bM;
  float* rin = rrA + bM;
  float* rou = rrB + bM;

  const float4* q1 = (const float4*)(xyz1 + (size_t)b * NPTS * 3);
  const float4* q2 = (const float4*)(xyz2 + bM * 3);

  // ---- init: stage raw coords once; zero t1 buf0/buf1, t9[b], outAcc[b] ----
  {
    float4* z0 = (float4*)cur;
    float4* z1 = (float4*)nxt;
    const float4 zz = make_float4(0.f, 0.f, 0.f, 0.f);
    for (int g = tid; g < MPTS / 4; g += BLOCK) {
      float4 a = q2[3 * g], bb = q2[3 * g + 1], c = q2[3 * g + 2];
      sP[4 * g + 0] = make_float4(a.x, a.y, a.z, 0.f);
      sP[4 * g + 1] = make_float4(a.w, bb.x, bb.y, 0.f);
      sP[4 * g + 2] = make_float4(bb.z, bb.w, c.x, 0.f);
      sP[4 * g + 3] = make_float4(c.y, c.z, c.w, 0.f);
      if (desig) { cohStore4(z0 + g, zz); cohStore4(z1 + g, zz); }
    }
    if (desig && tid == 0) {
      cohStore(t9 + b * PAD, 0.f);
      cohStore(outAcc + b * PAD, 0.f);
    }
  }
  __syncthreads();

  // ---- A0: rowscale_0, then t1_0 accumulation ----
  const float nc0 = -16384.0f * LOG2E;
  {
    const int ph = lane >> 1, rg = lane & 1;
    float x1a[8], y1a[8], z1a[8], acc[8];
    load8(q1, t0 + rg * 8, x1a, y1a, z1a);
#pragma unroll
    for (int j = 0; j < 8; ++j) acc[j] = 0.f;
    const int mb = wave * 512 + ph;
#pragma unroll 2
    for (int it = 0; it < 16; ++it) {
      float4 v = sP[mb + it * 32];
#pragma unroll
      for (int j = 0; j < 8; ++j) {
        float dx = x1a[j] - v.x, dy = y1a[j] - v.y, dz = z1a[j] - v.z;
        float d2 = __builtin_fmaf(dx, dx, __builtin_fmaf(dy, dy, dz * dz));
        acc[j] += fast_exp2(nc0 * d2);
      }
    }
#pragma unroll
    for (int j = 0; j < 8; ++j) {
      acc[j] += __shfl_xor(acc[j], 2, 64);
      acc[j] += __shfl_xor(acc[j], 4, 64);
      acc[j] += __shfl_xor(acc[j], 8, 64);
      acc[j] += __shfl_xor(acc[j], 16, 64);
      acc[j] += __shfl_xor(acc[j], 32, 64);
    }
    if (lane < 2) {
#pragma unroll
      for (int j = 0; j < 8; ++j) sRedS[(rg * 8 + j) * 4 + wave] = acc[j];
    }
    __syncthreads();
    if (tid < ROWS) {
      float s = sRedS[tid * 4] + sRedS[tid * 4 + 1] + sRedS[tid * 4 + 2] +
                sRedS[tid * 4 + 3];
      sRowScale[tid] = 1.0f / (s + 1e-9f);
    }
    // barrier 0: t1 buf zeroes + t9/outAcc zeroes visible before any atomics;
    // also the block barrier for sRowScale.
    batch_barrier(ctr + (0 * BATCH + b) * PAD);
    float rsn[8];
#pragma unroll
    for (int j = 0; j < 8; ++j) rsn[j] = sRowScale[rg * 8 + j];
#pragma unroll 2
    for (int it = 0; it < 16; ++it) {
      int idx = mb + it * 32;
      float4 v = sP[idx];
      float part = 0.f;
#pragma unroll
      for (int j = 0; j < 8; ++j) {
        float dx = x1a[j] - v.x, dy = y1a[j] - v.y, dz = z1a[j] - v.z;
        float d2 = __builtin_fmaf(dx, dx, __builtin_fmaf(dy, dy, dz * dz));
        part = __builtin_fmaf(fast_exp2(nc0 * d2), rsn[j], part);
      }
      part += __shfl_xor(part, 1, 64);
      if (rg == 0) atomicAdd(cur + idx, part);
    }
  }
  // barrier 1: t1_0 accumulation complete before level-0 staging reads it.
  batch_barrier(ctr + (1 * BATCH + b) * PAD);

  // ---- persistent CA row fragment (raw coords) ----
  float x1[4], y1[4], z1[4];
  {
    int b4 = ((t0 + (lane & 3) * 4) >> 2) * 3;
    float4 a = q1[b4], bb = q1[b4 + 1], c = q1[b4 + 2];
    x1[0] = a.x;  y1[0] = a.y;  z1[0] = a.z;
    x1[1] = a.w;  y1[1] = bb.x; z1[1] = bb.y;
    x1[2] = bb.z; y1[2] = bb.w; z1[2] = c.x;
    x1[3] = c.y;  y1[3] = c.z;  z1[3] = c.w;
  }
  const int phc = lane >> 2, rgc = lane & 3;
  const int mbc = wave * 512 + phc;

  float nc2 = -4096.0f * LOG2E;   // levels[l+1]*LOG2E; exact /4 per level
  for (int l = 0; l < 9; ++l) {
    const bool LAST = (l == 8);
    float rnsum = 0.f;
    {
      const float4* t14 = (const float4*)cur;
      const float4* rr4 = (const float4*)rin;
      float4* ro4 = (float4*)rou;
      float4* z4 = (float4*)zer;
      const float4 zz = make_float4(0.f, 0.f, 0.f, 0.f);
      for (int g = tid; g < MPTS / 4; g += BLOCK) {
        float4 t1v = cohLoad4(t14 + g);
        float4 rrv = (l == 0) ? make_float4(1.f, 1.f, 1.f, 1.f)
                              : cohLoad4(rr4 + g);
        float rrc[4] = {rrv.x, rrv.y, rrv.z, rrv.w};
        float t1c[4] = {t1v.x, t1v.y, t1v.z, t1v.w};
        float cc[4], rn[4];
#pragma unroll
        for (int i = 0; i < 4; ++i) {
          float colsum = rrc[i] * t1c[i];
          float cs = fminf(rrc[i] / (colsum + 1e-9f), 1.0f);
          cc[i] = rrc[i] * cs;
          rn[i] = fmaxf(rrc[i] - colsum * cs, 0.f);
        }
        rnsum += rn[0] + rn[1] + rn[2] + rn[3];
        sP[4 * g + 0].w = packh2(cc[0], rn[0]);
        sP[4 * g + 1].w = packh2(cc[1], rn[1]);
        sP[4 * g + 2].w = packh2(cc[2], rn[2]);
        sP[4 * g + 3].w = packh2(cc[3], rn[3]);
        if (desig) {
          cohStore4(ro4 + g, make_float4(rn[0], rn[1], rn[2], rn[3]));
          if (!LAST) cohStore4(z4 + g, zz);
        }
      }
      if (LAST) {   // R at last level = sum_m rn (e2 == 1)
        rnsum += __shfl_xor(rnsum, 1, 64);
        rnsum += __shfl_xor(rnsum, 2, 64);
        rnsum += __shfl_xor(rnsum, 4, 64);
        rnsum += __shfl_xor(rnsum, 8, 64);
        rnsum += __shfl_xor(rnsum, 16, 64);
        rnsum += __shfl_xor(rnsum, 32, 64);
        if (lane == 0) sRn[wave] = rnsum;
      }
    }
    __syncthreads();
    float accS[4] = {0.f, 0.f, 0.f, 0.f};
    float accC[4] = {0.f, 0.f, 0.f, 0.f};
    float accR[4] = {0.f, 0.f, 0.f, 0.f};
#pragma unroll 4
    for (int it = 0; it < 32; ++it) {
      float4 v = sP[mbc + it * 16];
      __half2 h = __builtin_bit_cast(__half2, v.w);
      float cc = __low2float(h);
      float rr = __high2float(h);
#pragma unroll
      for (int j = 0; j < 4; ++j) {
        float dx = x1[j] - v.x, dy = y1[j] - v.y, dz = z1[j] - v.z;
        float d2 = __builtin_fmaf(dx, dx, __builtin_fmaf(dy, dy, dz * dz));
        float sq = fast_sqrt(d2);
        float e2 = fast_exp2(nc2 * d2);
        float e2s = e2 * e2;
        float e1 = e2s * e2s;   // exp(levels[l]*d2); at LAST -> exp(-0.25 d2)
        float t = e1 * cc;
        accS[j] += t;
        accC[j] = __builtin_fmaf(t, sq, accC[j]);
        accR[j] = __builtin_fmaf(e2, rr, accR[j]);
      }
    }
#pragma unroll
    for (int j = 0; j < 4; ++j) {
      accS[j] += __shfl_xor(accS[j], 4, 64);
      accS[j] += __shfl_xor(accS[j], 8, 64);
      accS[j] += __shfl_xor(accS[j], 16, 64);
      accS[j] += __shfl_xor(accS[j], 32, 64);
      accC[j] += __shfl_xor(accC[j], 4, 64);
      accC[j] += __shfl_xor(accC[j], 8, 64);
      accC[j] += __shfl_xor(accC[j], 16, 64);
      accC[j] += __shfl_xor(accC[j], 32, 64);
      accR[j] += __shfl_xor(accR[j], 4, 64);
      accR[j] += __shfl_xor(accR[j], 8, 64);
      accR[j] += __shfl_xor(accR[j], 16, 64);
      accR[j] += __shfl_xor(accR[j], 32, 64);
    }
    if (lane < 4) {
#pragma unroll
      for (int j = 0; j < 4; ++j) {
        sRedS[(rgc * 4 + j) * 4 + wave] = accS[j];
        sRedC[(rgc * 4 + j) * 4 + wave] = accC[j];
        sRedR[(rgc * 4 + j) * 4 + wave] = accR[j];
      }
    }
    __syncthreads();
    if (tid < ROWS) {
      float S2 = sRedS[tid * 4] + sRedS[tid * 4 + 1] + sRedS[tid * 4 + 2] +
                 sRedS[tid * 4 + 3];
      float C = sRedC[tid * 4] + sRedC[tid * 4 + 1] + sRedC[tid * 4 + 2] +
                sRedC[tid * 4 + 3];
      float R = sRedR[tid * 4] + sRedR[tid * 4 + 1] + sRedR[tid * 4 + 2] +
                sRedR[tid * 4 + 3];
      if (LAST) R = sRn[0] + sRn[1] + sRn[2] + sRn[3];
      float rs = sRowScale[tid];
      float rl = (l == 0) ? 1.0f : sRemainL[tid];
      float rlN = fmaxf(rl - rs * S2, 0.f);
      sRemainL[tid] = rlN;
      sRowScale[tid] = rlN / (R + 1e-9f);
      sCost[tid] = rs * C;
    }
    __syncthreads();
    if (tid == 0) {
      float t = 0.f;
#pragma unroll
      for (int i = 0; i < ROWS; ++i) t += sCost[i];
      costAcc += t;                       // DEFERRED: no out atomic per level
      if (LAST) {
        float r = 0.f;
#pragma unroll
        for (int i = 0; i < ROWS; ++i) r += sRowScale[i];
        atomicAdd(t9 + b * PAD, r);       // padded: own 64B line per batch
      }
    }
    if (!LAST) {
      float rsn[4];
#pragma unroll
      for (int j = 0; j < 4; ++j) rsn[j] = sRowScale[rgc * 4 + j];
#pragma unroll 4
      for (int it = 0; it < 32; ++it) {
        int idx = mbc + it * 16;
        float4 v = sP[idx];
        float part = 0.f;
#pragma unroll
        for (int j = 0; j < 4; ++j) {
          float dx = x1[j] - v.x, dy = y1[j] - v.y, dz = z1[j] - v.z;
          float d2 = __builtin_fmaf(dx, dx, __builtin_fmaf(dy, dy, dz * dz));
          part = __builtin_fmaf(fast_exp2(nc2 * d2), rsn[j], part);
        }
        part += __shfl_xor(part, 1, 64);
        part += __shfl_xor(part, 2, 64);
        if (rgc == 0) atomicAdd(nxt + idx, part);
      }
    }
    // barrier 2+l: t1_{l+1} accumulation + rr_{l+1} stores complete.
    batch_barrier(ctr + ((2 + l) * BATCH + b) * PAD);
    if (!LAST) {
      float* tp = cur; cur = nxt; nxt = zer; zer = tp;
      float* tr = rin; rin = rou; rou = tr;
      nc2 *= 0.25f;
    }
  }

  // ---- C9 (lvl=0): t1 scalar = t9[b]; cost with unscaled coords ----
  {
    const float t1 = cohLoad(t9 + b * PAD);
    const float4* rr4 = (const float4*)rou;   // rr_9 (no rotate at LAST)
    for (int g = tid; g < MPTS / 4; g += BLOCK) {
      float4 rr = cohLoad4(rr4 + g);
      sP[4 * g + 0].w = rr.x * fminf(rr.x / (__builtin_fmaf(rr.x, t1, 1e-9f)), 1.0f);
      sP[4 * g + 1].w = rr.y * fminf(rr.y / (__builtin_fmaf(rr.y, t1, 1e-9f)), 1.0f);
      sP[4 * g + 2].w = rr.z * fminf(rr.z / (__builtin_fmaf(rr.z, t1, 1e-9f)), 1.0f);
      sP[4 * g + 3].w = rr.w * fminf(rr.w / (__builtin_fmaf(rr.w, t1, 1e-9f)), 1.0f);
    }
    __syncthreads();
    const int ph = lane >> 1, rg = lane & 1;
    float x1a[8], y1a[8], z1a[8], acc[8];
    load8(q1, t0 + rg * 8, x1a, y1a, z1a);
#pragma unroll
    for (int j = 0; j < 8; ++j) acc[j] = 0.f;
    const int mb = wave * 512 + ph;
#pragma unroll 2
    for (int it = 0; it < 16; ++it) {
      float4 v = sP[mb + it * 32];
#pragma unroll
      for (int j = 0; j < 8; ++j) {
        float dx = x1a[j] - v.x, dy = y1a[j] - v.y, dz = z1a[j] - v.z;
        float d2 = __builtin_fmaf(dx, dx, __builtin_fmaf(dy, dy, dz * dz));
        acc[j] = __builtin_fmaf(fast_sqrt(d2), v.w, acc[j]);
      }
    }
#pragma unroll
    for (int j = 0; j < 8; ++j) {
      acc[j] += __shfl_xor(acc[j], 2, 64);
      acc[j] += __shfl_xor(acc[j], 4, 64);
      acc[j] += __shfl_xor(acc[j], 8, 64);
      acc[j] += __shfl_xor(acc[j], 16, 64);
      acc[j] += __shfl_xor(acc[j], 32, 64);
    }
    if (lane < 2) {
#pragma unroll
      for (int j = 0; j < 8; ++j) sRedS[(rg * 8 + j) * 4 + wave] = acc[j];
    }
    __syncthreads();
    if (tid < ROWS) {
      float C = sRedS[tid * 4] + sRedS[tid * 4 + 1] + sRedS[tid * 4 + 2] +
                sRedS[tid * 4 + 3];
      sCost[tid] = sRowScale[tid] * C;
    }
    __syncthreads();
    if (tid == 0) {
      float t = 0.f;
#pragma unroll
      for (int i = 0; i < ROWS; ++i) t += sCost[i];
      costAcc += t;
      // ONE atomic per block for the whole kernel, into a padded per-batch
      // slot (128-deep chain per line, batches in parallel).
      atomicAdd(outAcc + b * PAD, costAcc);
    }
  }
  // barrier 11: all outAcc contributions complete.
  batch_barrier(ctr + (11 * BATCH + b) * PAD);
  if (desig && tid == 0) out[b] = cohLoad(outAcc + b * PAD);
}

// ---------------------------------------------------------------------------
extern "C" void kernel_launch(void* const* d_in, const int* in_sizes, int n_in,
                              void* d_out, int out_size, void* d_ws, size_t ws_size,
                              hipStream_t stream) {
  const float* xyz1 = (const float*)d_in[0];
  const float* xyz2 = (const float*)d_in[1];
  float* out = (float*)d_out;
  float* ws = (float*)d_ws;

  const int BM = BATCH * MPTS;
  float* rrA    = ws;                        // BM
  float* rrB    = ws + BM;                   // BM
  float* t1b    = ws + 2 * BM;               // 3*BM (triple buffer)
  float* t9     = ws + 5 * BM;               // BATCH*PAD (64B/line per batch)
  float* outAcc = ws + 5 * BM + BATCH * PAD; // BATCH*PAD
  unsigned* ctr = (unsigned*)(ws + 5 * BM + 2 * BATCH * PAD); // NSYNC*BATCH*PAD

  // zero barrier counters (keeps them multiples of 128 across graph replays)
  hipMemsetAsync(ctr, 0, NSYNC * BATCH * PAD * sizeof(unsigned), stream);

  void* args[] = {(void*)&xyz1, (void*)&xyz2, (void*)&out, (void*)&t1b,
                  (void*)&rrA, (void*)&rrB, (void*)&t9, (void*)&outAcc,
                  (void*)&ctr};
  hipLaunchKernel((const void*)emd_fused_kernel,
                  dim3(BATCH * (NPTS / ROWS)), dim3(BLOCK), args, 0, stream);
}

// Round 6
// 427.040 us; speedup vs baseline: 1.8054x; 1.0572x over previous
//
#include <hip/hip_runtime.h>
#include <hip/hip_fp16.h>

// EMD approx-match (auction) + match_cost, fully fused, ONE normal launch.
// R20: t1 atomics eliminated by TRANSPOSED ownership. R19 left ~216us stall:
// t1 atomicAdd tails (~2048 RMWs per 64B line at the LLC; stagger-null =>
// throughput-bound) + 128-deep barrier arrive chains. Changes:
// (1) sweep2 -> sweep2T: each block OWNS m-slice [t0,t0+16) and computes
//     t1[m] = sum_n e(n,m)*rsN[n] itself (same FLOPs, zero atomics). xyz1+rs
//     staged per 256-n chunk in 4KB LDS (16x redundancy removed).
// (2) rr[m] persists in owner LDS across levels (global rr ping-pong gone);
//     owner fuses cc/rn clipping once per m, publishes half2(cc,rn) as one
//     float -> staging is a pure 8KB coherent read (was 16KB + VALU).
// (3) barriers: 8 sub-counters x 16-deep chains on separate 64B lines,
//     absolute target (ctr memset per launch). 21 barriers @ ~1-2us.
// (4) R9 (=sum rn_9) and t9 (=sum rsN_9): one padded atomicAdd per block.

#define BATCH 8
#define NPTS 2048
#define MPTS 2048
#define BLOCK 256
#define ROWS 16
#define BLOCKS_PER_BATCH 128
#define NSUB 8
#define SUBTGT (BLOCKS_PER_BATCH / NSUB)   // 16
#define NSYNC 21
#define PAD 16                             // dwords per 64B line
#define LOG2E 1.44269504088896340736f

__device__ __forceinline__ float fast_exp2(float x) {
  return __builtin_amdgcn_exp2f(x);     // v_exp_f32
}
__device__ __forceinline__ float fast_sqrt(float a) {
  return __builtin_amdgcn_sqrtf(a);     // v_sqrt_f32
}
__device__ __forceinline__ float packh2(float c, float r) {
  __half2 h = __halves2half2(__float2half_rn(c), __float2half_rn(r));
  return __builtin_bit_cast(float, h);
}

// ---- agent-scope coherent access helpers (bypass non-coherent XCD L2) ----
__device__ __forceinline__ float cohLoad(const float* p) {
  return __hip_atomic_load((float*)p, __ATOMIC_RELAXED,
                           __HIP_MEMORY_SCOPE_AGENT);
}
__device__ __forceinline__ void cohStore(float* p, float v) {
  __hip_atomic_store(p, v, __ATOMIC_RELAXED, __HIP_MEMORY_SCOPE_AGENT);
}
__device__ __forceinline__ float4 cohLoad4(const float4* p) {
  const float* f = (const float*)p;
  return make_float4(cohLoad(f), cohLoad(f + 1), cohLoad(f + 2),
                     cohLoad(f + 3));
}

// Per-batch grid barrier, two-level: 8 sub-counters (own 64B line each),
// 16 arrivals per sub. Absolute target (counters memset each launch; the
// memset node replays in graph). __syncthreads before arrive drains
// vmcnt(0) per wave -> all block writes/atomics complete at the coherent
// point before the arrive. Bounded spin: fail fast, never hang.
__device__ __forceinline__ void batch_barrier(unsigned* base, int bid) {
  __syncthreads();
  if (threadIdx.x == 0) {
    __hip_atomic_fetch_add(base + (bid & (NSUB - 1)) * PAD, 1u,
                           __ATOMIC_RELAXED, __HIP_MEMORY_SCOPE_AGENT);
  }
  if (threadIdx.x < NSUB) {
    int guard = 0;
    while (__hip_atomic_load(base + threadIdx.x * PAD, __ATOMIC_RELAXED,
                             __HIP_MEMORY_SCOPE_AGENT) < (unsigned)SUBTGT) {
      __builtin_amdgcn_s_sleep(2);
      if (++guard > (1 << 22)) break;
    }
  }
  asm volatile("" ::: "memory");
  __syncthreads();
}

// Load 8 consecutive points (r0 multiple of 8) as 6 float4s (raw).
__device__ __forceinline__ void load8(const float4* q, int r0,
                                      float* x, float* y, float* z) {
  int b4 = (r0 >> 2) * 3;
  float4 q0 = q[b4], q1 = q[b4 + 1], q2 = q[b4 + 2];
  float4 q3 = q[b4 + 3], q4 = q[b4 + 4], q5 = q[b4 + 5];
  x[0] = q0.x; y[0] = q0.y; z[0] = q0.z;
  x[1] = q0.w; y[1] = q1.x; z[1] = q1.y;
  x[2] = q1.z; y[2] = q1.w; z[2] = q2.x;
  x[3] = q2.y; y[3] = q2.z; z[3] = q2.w;
  x[4] = q3.x; y[4] = q3.y; z[4] = q3.z;
  x[5] = q3.w; y[5] = q4.x; z[5] = q4.y;
  x[6] = q4.z; y[6] = q4.w; z[6] = q5.x;
  x[7] = q5.y; y[7] = q5.z; z[7] = q5.w;
}

// Transposed t1 sweep + owner fusion. Thread t: m_idx=t>>4 (owned m =
// t0+m_idx), c=t&15 covers n in 16-pt strips per 256-n chunk. xyz1 (plain,
// immutable) + rsN (coherent) staged in sStage4 (4KB). After reduce over the
// 16-lane group, lane c==0 fuses the clipping: colsum=rr*t1, cc, rn;
// publishes wPack[m]=half2(cc,rn); sRR[m_idx]=rn (rr for next level).
__device__ __forceinline__ void sweep2T_fuse(
    float nc, int tid, int t0, const float4* q1, const float* rsG,
    float* wpB, const float4* sP, float4* sStage4, float* sRR) {
  const int m_idx = tid >> 4, c = tid & 15;
  const float4 pm = sP[t0 + m_idx];
  const float4* rsg4 = (const float4*)rsG;
  float part = 0.f;
  for (int chunk = 0; chunk < 8; ++chunk) {
    __syncthreads();
    if (tid < 192) sStage4[tid] = q1[chunk * 192 + tid];
    else           sStage4[tid] = cohLoad4(rsg4 + chunk * 64 + (tid - 192));
    __syncthreads();
#pragma unroll
    for (int k = 0; k < 4; ++k) {
      float4 a  = sStage4[c * 12 + 3 * k];
      float4 bb = sStage4[c * 12 + 3 * k + 1];
      float4 cc = sStage4[c * 12 + 3 * k + 2];
      float4 r4 = sStage4[192 + c * 4 + k];
      float px[4] = {a.x, a.w, bb.z, cc.y};
      float py[4] = {a.y, bb.x, bb.w, cc.z};
      float pz[4] = {a.z, bb.y, cc.x, cc.w};
      float rr[4] = {r4.x, r4.y, r4.z, r4.w};
#pragma unroll
      for (int j = 0; j < 4; ++j) {
        float dx = px[j] - pm.x, dy = py[j] - pm.y, dz = pz[j] - pm.z;
        float d2 = __builtin_fmaf(dx, dx, __builtin_fmaf(dy, dy, dz * dz));
        part = __builtin_fmaf(fast_exp2(nc * d2), rr[j], part);
      }
    }
  }
  part += __shfl_xor(part, 1, 64);
  part += __shfl_xor(part, 2, 64);
  part += __shfl_xor(part, 4, 64);
  part += __shfl_xor(part, 8, 64);
  if (c == 0) {
    float t1v = part;
    float rr = sRR[m_idx];
    float colsum = rr * t1v;
    float cs = fminf(rr / (colsum + 1e-9f), 1.0f);
    float ccv = rr * cs;
    float rn = fmaxf(rr - colsum * cs, 0.f);
    cohStore(wpB + t0 + m_idx, packh2(ccv, rn));
    sRR[m_idx] = rn;
  }
}

__global__ __launch_bounds__(BLOCK, 4) void emd_fused_kernel(
    const float* __restrict__ xyz1, const float* __restrict__ xyz2,
    float* __restrict__ out, float* __restrict__ rowscaleG,
    float* __restrict__ wPack, float* __restrict__ R9acc,
    float* __restrict__ t9, float* __restrict__ outAcc,
    unsigned* __restrict__ ctr) {
  __shared__ float4 sP[MPTS];          // raw x2,y2,z2; w = per-level payload
  __shared__ float4 sStage4[256];      // sweep2T chunk: xyz1(192) + rs(64)
  __shared__ float sRedS[ROWS * 4];
  __shared__ float sRedC[ROWS * 4];
  __shared__ float sRedR[ROWS * 4];
  __shared__ float sCost[ROWS];
  __shared__ float sRowScale[ROWS];    // persistent across levels
  __shared__ float sRemainL[ROWS];     // persistent across levels
  __shared__ float sRR[ROWS];          // owner's rr slice, full precision

  const int tid = threadIdx.x;
  const int bid = blockIdx.x;
  const int b = bid >> 7;
  const int t0 = (bid & 127) * ROWS;
  const bool desig = (bid & 127) == 0;
  const int wave = tid >> 6, lane = tid & 63;
  const size_t bM = (size_t)b * MPTS;
  float costAcc = 0.f;                 // meaningful on tid==0

  float* rsG = rowscaleG + (size_t)b * NPTS;
  float* wpB = wPack + bM;
  const float4* q1 = (const float4*)(xyz1 + (size_t)b * NPTS * 3);
  const float4* q2 = (const float4*)(xyz2 + bM * 3);
#define CTRB(s) (ctr + (size_t)(((s) * BATCH + b) * NSUB) * PAD)

  // ---- init: stage raw xyz2; rr_0 = 1; zero scalar accumulators ----
  for (int g = tid; g < MPTS / 4; g += BLOCK) {
    float4 a = q2[3 * g], bb = q2[3 * g + 1], c = q2[3 * g + 2];
    sP[4 * g + 0] = make_float4(a.x, a.y, a.z, 0.f);
    sP[4 * g + 1] = make_float4(a.w, bb.x, bb.y, 0.f);
    sP[4 * g + 2] = make_float4(bb.z, bb.w, c.x, 0.f);
    sP[4 * g + 3] = make_float4(c.y, c.z, c.w, 0.f);
  }
  if (tid < ROWS) sRR[tid] = 1.0f;
  if (desig && tid == 0) {
    cohStore(R9acc + b * PAD, 0.f);
    cohStore(t9 + b * PAD, 0.f);
    cohStore(outAcc + b * PAD, 0.f);
  }
  __syncthreads();

  // ---- A0: rowscale_0 ----
  const float nc0 = -16384.0f * LOG2E;
  {
    const int ph = lane >> 1, rg = lane & 1;
    float x1a[8], y1a[8], z1a[8], acc[8];
    load8(q1, t0 + rg * 8, x1a, y1a, z1a);
#pragma unroll
    for (int j = 0; j < 8; ++j) acc[j] = 0.f;
    const int mb = wave * 512 + ph;
#pragma unroll 2
    for (int it = 0; it < 16; ++it) {
      float4 v = sP[mb + it * 32];
#pragma unroll
      for (int j = 0; j < 8; ++j) {
        float dx = x1a[j] - v.x, dy = y1a[j] - v.y, dz = z1a[j] - v.z;
        float d2 = __builtin_fmaf(dx, dx, __builtin_fmaf(dy, dy, dz * dz));
        acc[j] += fast_exp2(nc0 * d2);
      }
    }
#pragma unroll
    for (int j = 0; j < 8; ++j) {
      acc[j] += __shfl_xor(acc[j], 2, 64);
      acc[j] += __shfl_xor(acc[j], 4, 64);
      acc[j] += __shfl_xor(acc[j], 8, 64);
      acc[j] += __shfl_xor(acc[j], 16, 64);
      acc[j] += __shfl_xor(acc[j], 32, 64);
    }
    if (lane < 2) {
#pragma unroll
      for (int j = 0; j < 8; ++j) sRedS[(rg * 8 + j) * 4 + wave] = acc[j];
    }
    __syncthreads();
    if (tid < ROWS) {
      float s = sRedS[tid * 4] + sRedS[tid * 4 + 1] + sRedS[tid * 4 + 2] +
                sRedS[tid * 4 + 3];
      float rs = 1.0f / (s + 1e-9f);
      sRowScale[tid] = rs;
      cohStore(rsG + t0 + tid, rs);
    }
  }
  batch_barrier(CTRB(0), bid);          // rs_0 + init zeroes visible
  sweep2T_fuse(nc0, tid, t0, q1, rsG, wpB, sP, sStage4, sRR);  // -> wPack_0
  batch_barrier(CTRB(1), bid);          // wPack_0 visible

  // ---- persistent CA row fragment (raw coords) ----
  float x1[4], y1[4], z1[4];
  {
    int b4 = ((t0 + (lane & 3) * 4) >> 2) * 3;
    float4 a = q1[b4], bb = q1[b4 + 1], c = q1[b4 + 2];
    x1[0] = a.x;  y1[0] = a.y;  z1[0] = a.z;
    x1[1] = a.w;  y1[1] = bb.x; z1[1] = bb.y;
    x1[2] = bb.z; y1[2] = bb.w; z1[2] = c.x;
    x1[3] = c.y;  y1[3] = c.z;  z1[3] = c.w;
  }
  const int phc = lane >> 2, rgc = lane & 3;
  const int mbc = wave * 512 + phc;

  float nc2 = -4096.0f * LOG2E;   // levels[l+1]*LOG2E; exact /4 per level
  for (int l = 0; l < 9; ++l) {
    const bool LAST = (l == 8);
    // -- staging: sP.w = wPack_l (pure coherent read; clipping pre-done) --
    {
      const float4* wp4 = (const float4*)wpB;
      for (int g = tid; g < MPTS / 4; g += BLOCK) {
        float4 w4 = cohLoad4(wp4 + g);
        sP[4 * g + 0].w = w4.x;
        sP[4 * g + 1].w = w4.y;
        sP[4 * g + 2].w = w4.z;
        sP[4 * g + 3].w = w4.w;
      }
    }
    __syncthreads();
    // -- sweep1: cost(l) + remainL + rowscale(l+1). e1 = e2^4 (exact). --
    float accS[4] = {0.f, 0.f, 0.f, 0.f};
    float accC[4] = {0.f, 0.f, 0.f, 0.f};
    float accR[4] = {0.f, 0.f, 0.f, 0.f};
#pragma unroll 4
    for (int it = 0; it < 32; ++it) {
      float4 v = sP[mbc + it * 16];
      __half2 h = __builtin_bit_cast(__half2, v.w);
      float cc = __low2float(h);
      float rr = __high2float(h);
#pragma unroll
      for (int j = 0; j < 4; ++j) {
        float dx = x1[j] - v.x, dy = y1[j] - v.y, dz = z1[j] - v.z;
        float d2 = __builtin_fmaf(dx, dx, __builtin_fmaf(dy, dy, dz * dz));
        float sq = fast_sqrt(d2);
        float e2 = fast_exp2(nc2 * d2);
        float e2s = e2 * e2;
        float e1 = e2s * e2s;   // exp(levels[l]*d2); at LAST -> exp(-0.25 d2)
        float t = e1 * cc;
        accS[j] += t;
        accC[j] = __builtin_fmaf(t, sq, accC[j]);
        accR[j] = __builtin_fmaf(e2, rr, accR[j]);
      }
    }
#pragma unroll
    for (int j = 0; j < 4; ++j) {
      accS[j] += __shfl_xor(accS[j], 4, 64);
      accS[j] += __shfl_xor(accS[j], 8, 64);
      accS[j] += __shfl_xor(accS[j], 16, 64);
      accS[j] += __shfl_xor(accS[j], 32, 64);
      accC[j] += __shfl_xor(accC[j], 4, 64);
      accC[j] += __shfl_xor(accC[j], 8, 64);
      accC[j] += __shfl_xor(accC[j], 16, 64);
      accC[j] += __shfl_xor(accC[j], 32, 64);
      accR[j] += __shfl_xor(accR[j], 4, 64);
      accR[j] += __shfl_xor(accR[j], 8, 64);
      accR[j] += __shfl_xor(accR[j], 16, 64);
      accR[j] += __shfl_xor(accR[j], 32, 64);
    }
    if (lane < 4) {
#pragma unroll
      for (int j = 0; j < 4; ++j) {
        sRedS[(rgc * 4 + j) * 4 + wave] = accS[j];
        sRedC[(rgc * 4 + j) * 4 + wave] = accC[j];
        sRedR[(rgc * 4 + j) * 4 + wave] = accR[j];
      }
    }
    __syncthreads();
    if (tid < ROWS) {
      float S2 = sRedS[tid * 4] + sRedS[tid * 4 + 1] + sRedS[tid * 4 + 2] +
                 sRedS[tid * 4 + 3];
      float C = sRedC[tid * 4] + sRedC[tid * 4 + 1] + sRedC[tid * 4 + 2] +
                sRedC[tid * 4 + 3];
      float R = sRedR[tid * 4] + sRedR[tid * 4 + 1] + sRedR[tid * 4 + 2] +
                sRedR[tid * 4 + 3];
      if (LAST) R = cohLoad(R9acc + b * PAD);   // sum_m rr_9 (e == 1)
      float rs = sRowScale[tid];
      float rl = (l == 0) ? 1.0f : sRemainL[tid];
      float rlN = fmaxf(rl - rs * S2, 0.f);
      sRemainL[tid] = rlN;
      float rsN = rlN / (R + 1e-9f);
      sRowScale[tid] = rsN;
      if (!LAST) cohStore(rsG + t0 + tid, rsN);
      sCost[tid] = rs * C;
    }
    __syncthreads();
    if (tid == 0) {
      float t = 0.f;
#pragma unroll
      for (int i = 0; i < ROWS; ++i) t += sCost[i];
      costAcc += t;
      if (LAST) {
        float r = 0.f;
#pragma unroll
        for (int i = 0; i < ROWS; ++i) r += sRowScale[i];
        atomicAdd(t9 + b * PAD, r);       // one per block, padded line
      }
    }
    if (!LAST) {
      batch_barrier(CTRB(2 + 2 * l), bid);    // rsN_{l+1} visible
      sweep2T_fuse(nc2, tid, t0, q1, rsG, wpB, sP, sStage4, sRR);
      if (l == 7) {          // R9 = sum_m rr_9: block partial, one atomic
        __syncthreads();
        if (tid == 0) {
          float r9 = 0.f;
#pragma unroll
          for (int i = 0; i < ROWS; ++i) r9 += sRR[i];
          atomicAdd(R9acc + b * PAD, r9);
        }
      }
      batch_barrier(CTRB(3 + 2 * l), bid);    // wPack_{l+1} (+R9acc) visible
      nc2 *= 0.25f;
    }
  }
  batch_barrier(CTRB(18), bid);               // t9 complete

  // ---- C9 owner publish: w[m] from full-precision rr_9 + t9 ----
  if (tid < ROWS) {
    float rr = sRR[tid];
    float t1s = cohLoad(t9 + b * PAD);
    float w = rr * fminf(rr / (__builtin_fmaf(rr, t1s, 1e-9f)), 1.0f);
    cohStore(wpB + t0 + tid, w);              // full float (matches old C9)
  }
  batch_barrier(CTRB(19), bid);               // w visible

  // ---- C9 (lvl=0): cost with unscaled coords ----
  {
    const float4* wp4 = (const float4*)wpB;
    for (int g = tid; g < MPTS / 4; g += BLOCK) {
      float4 w4 = cohLoad4(wp4 + g);
      sP[4 * g + 0].w = w4.x;
      sP[4 * g + 1].w = w4.y;
      sP[4 * g + 2].w = w4.z;
      sP[4 * g + 3].w = w4.w;
    }
    __syncthreads();
    const int ph = lane >> 1, rg = lane & 1;
    float x1a[8], y1a[8], z1a[8], acc[8];
    load8(q1, t0 + rg * 8, x1a, y1a, z1a);
#pragma unroll
    for (int j = 0; j < 8; ++j) acc[j] = 0.f;
    const int mb = wave * 512 + ph;
#pragma unroll 2
    for (int it = 0; it < 16; ++it) {
      float4 v = sP[mb + it * 32];
#pragma unroll
      for (int j = 0; j < 8; ++j) {
        float dx = x1a[j] - v.x, dy = y1a[j] - v.y, dz = z1a[j] - v.z;
        float d2 = __builtin_fmaf(dx, dx, __builtin_fmaf(dy, dy, dz * dz));
        acc[j] = __builtin_fmaf(fast_sqrt(d2), v.w, acc[j]);
      }
    }
#pragma unroll
    for (int j = 0; j < 8; ++j) {
      acc[j] += __shfl_xor(acc[j], 2, 64);
      acc[j] += __shfl_xor(acc[j], 4, 64);
      acc[j] += __shfl_xor(acc[j], 8, 64);
      acc[j] += __shfl_xor(acc[j], 16, 64);
      acc[j] += __shfl_xor(acc[j], 32, 64);
    }
    if (lane < 2) {
#pragma unroll
      for (int j = 0; j < 8; ++j) sRedS[(rg * 8 + j) * 4 + wave] = acc[j];
    }
    __syncthreads();
    if (tid < ROWS) {
      float C = sRedS[tid * 4] + sRedS[tid * 4 + 1] + sRedS[tid * 4 + 2] +
                sRedS[tid * 4 + 3];
      sCost[tid] = sRowScale[tid] * C;
    }
    __syncthreads();
    if (tid == 0) {
      float t = 0.f;
#pragma unroll
      for (int i = 0; i < ROWS; ++i) t += sCost[i];
      costAcc += t;
      atomicAdd(outAcc + b * PAD, costAcc);   // ONE atomic per block total
    }
  }
  batch_barrier(CTRB(20), bid);               // outAcc complete
  if (desig && tid == 0) out[b] = cohLoad(outAcc + b * PAD);
#undef CTRB
}

// ---------------------------------------------------------------------------
extern "C" void kernel_launch(void* const* d_in, const int* in_sizes, int n_in,
                              void* d_out, int out_size, void* d_ws, size_t ws_size,
                              hipStream_t stream) {
  const float* xyz1 = (const float*)d_in[0];
  const float* xyz2 = (const float*)d_in[1];
  float* out = (float*)d_out;
  float* ws = (float*)d_ws;

  const int BM = BATCH * MPTS;               // 16384
  float* rowscaleG = ws;                     // BM
  float* wPack     = ws + BM;                // BM
  float* R9acc     = ws + 2 * BM;            // BATCH*PAD
  float* t9        = ws + 2 * BM + BATCH * PAD;      // BATCH*PAD
  float* outAcc    = ws + 2 * BM + 2 * BATCH * PAD;  // BATCH*PAD
  unsigned* ctr    = (unsigned*)(ws + 2 * BM + 3 * BATCH * PAD);
  // ctr: NSYNC*BATCH*NSUB*PAD u32 = 21*8*8*16 = 21504 u32 (~86KB)

  hipMemsetAsync(ctr, 0, (size_t)NSYNC * BATCH * NSUB * PAD * sizeof(unsigned),
                 stream);

  void* args[] = {(void*)&xyz1, (void*)&xyz2, (void*)&out, (void*)&rowscaleG,
                  (void*)&wPack, (void*)&R9acc, (void*)&t9, (void*)&outAcc,
                  (void*)&ctr};
  hipLaunchKernel((const void*)emd_fused_kernel,
                  dim3(BATCH * (NPTS / ROWS)), dim3(BLOCK), args, 0, stream);
}

// Round 7
// 377.970 us; speedup vs baseline: 2.0397x; 1.1298x over previous
//
#include <hip/hip_runtime.h>
#include <hip/hip_fp16.h>

// EMD approx-match (auction) + match_cost, fully fused, ONE normal launch.
// R21: R20 (400us) proved transposed ownership (WRITE 79->2.5MB) but its
// sweep2T introduced 6.78e7 LDS bank-conflict cycles (row stride 12 f4 ->
// start bank 16(c&1): 8-way on every staged read) and ~25us/block of exposed
// LLC latency (no chunk prefetch; __syncthreads drains vmcnt). Fixes:
// (1) sStage rows padded to 17 float4s (xyz 12 + rs 4 + 1 pad) -> start
//     banks 4c%32, 2-way (free).
// (2) register-prefetch chunk pipeline with lgkm-only barriers
//     (s_waitcnt lgkmcnt(0) + s_barrier + sched_barrier(0)) so the next
//     chunk's global/coherent loads stay in flight across the barrier; the
//     dependent ds_write auto-waits (compiler-tracked vmcnt).
// (3) per-level .w staging: stride-256 scalar pattern (8-way writes, was
//     32-way; .w lives in only 8 of 32 banks -> >=8-way inherent).
// Everything else identical to R20.

#define BATCH 8
#define NPTS 2048
#define MPTS 2048
#define BLOCK 256
#define ROWS 16
#define BLOCKS_PER_BATCH 128
#define NSUB 8
#define SUBTGT (BLOCKS_PER_BATCH / NSUB)   // 16
#define NSYNC 21
#define PAD 16                             // dwords per 64B line
#define SROW 17                            // padded staging row, float4s
#define LOG2E 1.44269504088896340736f

__device__ __forceinline__ float fast_exp2(float x) {
  return __builtin_amdgcn_exp2f(x);     // v_exp_f32
}
__device__ __forceinline__ float fast_sqrt(float a) {
  return __builtin_amdgcn_sqrtf(a);     // v_sqrt_f32
}
__device__ __forceinline__ float packh2(float c, float r) {
  __half2 h = __halves2half2(__float2half_rn(c), __float2half_rn(r));
  return __builtin_bit_cast(float, h);
}

// ---- agent-scope coherent access helpers (bypass non-coherent XCD L2) ----
__device__ __forceinline__ float cohLoad(const float* p) {
  return __hip_atomic_load((float*)p, __ATOMIC_RELAXED,
                           __HIP_MEMORY_SCOPE_AGENT);
}
__device__ __forceinline__ void cohStore(float* p, float v) {
  __hip_atomic_store(p, v, __ATOMIC_RELAXED, __HIP_MEMORY_SCOPE_AGENT);
}
__device__ __forceinline__ float4 cohLoad4(const float4* p) {
  const float* f = (const float*)p;
  return make_float4(cohLoad(f), cohLoad(f + 1), cohLoad(f + 2),
                     cohLoad(f + 3));
}

// LDS-only barrier: waits DS ops (lgkm) but leaves global/coherent loads
// (vmcnt) in flight -- __syncthreads would drain vmcnt(0) and kill the
// chunk prefetch. sched_barrier(0) pins hipcc from hoisting past it (#18).
__device__ __forceinline__ void lds_barrier() {
  asm volatile("s_waitcnt lgkmcnt(0)" ::: "memory");
  __builtin_amdgcn_s_barrier();
  __builtin_amdgcn_sched_barrier(0);
}

// Per-batch grid barrier, two-level: 8 sub-counters (own 64B line each),
// 16 arrivals per sub. Absolute target (counters memset each launch).
// __syncthreads before arrive drains vmcnt(0) per wave -> all block
// writes/atomics complete at the coherent point before the arrive.
__device__ __forceinline__ void batch_barrier(unsigned* base, int bid) {
  __syncthreads();
  if (threadIdx.x == 0) {
    __hip_atomic_fetch_add(base + (bid & (NSUB - 1)) * PAD, 1u,
                           __ATOMIC_RELAXED, __HIP_MEMORY_SCOPE_AGENT);
  }
  if (threadIdx.x < NSUB) {
    int guard = 0;
    while (__hip_atomic_load(base + threadIdx.x * PAD, __ATOMIC_RELAXED,
                             __HIP_MEMORY_SCOPE_AGENT) < (unsigned)SUBTGT) {
      __builtin_amdgcn_s_sleep(2);
      if (++guard > (1 << 22)) break;
    }
  }
  asm volatile("" ::: "memory");
  __syncthreads();
}

// Load 8 consecutive points (r0 multiple of 8) as 6 float4s (raw).
__device__ __forceinline__ void load8(const float4* q, int r0,
                                      float* x, float* y, float* z) {
  int b4 = (r0 >> 2) * 3;
  float4 q0 = q[b4], q1 = q[b4 + 1], q2 = q[b4 + 2];
  float4 q3 = q[b4 + 3], q4 = q[b4 + 4], q5 = q[b4 + 5];
  x[0] = q0.x; y[0] = q0.y; z[0] = q0.z;
  x[1] = q0.w; y[1] = q1.x; z[1] = q1.y;
  x[2] = q1.z; y[2] = q1.w; z[2] = q2.x;
  x[3] = q2.y; y[3] = q2.z; z[3] = q2.w;
  x[4] = q3.x; y[4] = q3.y; z[4] = q3.z;
  x[5] = q3.w; y[5] = q4.x; z[5] = q4.y;
  x[6] = q4.z; y[6] = q4.w; z[6] = q5.x;
  x[7] = q5.y; y[7] = q5.z; z[7] = q5.w;
}

// Transposed t1 sweep + owner fusion. Thread t: m_idx=t>>4 (owned m =
// t0+m_idx), c=t&15 covers points [c*16,(c+1)*16) of each 256-n chunk.
// Padded-row staging (SROW=17): row c = 12 xyz f4 + 4 rs f4 + 1 pad ->
// conflict-free reads. Chunk loop is register-prefetched: next chunk's
// loads issue before compute, lgkm-only barriers keep them in flight.
__device__ __forceinline__ void sweep2T_fuse(
    float nc, int tid, int t0, const float4* q1, const float* rsG,
    float* wpB, const float4* sP, float4* sStage4, float* sRR) {
  const int m_idx = tid >> 4, c = tid & 15;
  const float4 pm = sP[t0 + m_idx];
  const float4* rsg4 = (const float4*)rsG;
  const int rowb = c * SROW;
  const bool isXyz = tid < 192;
  const int t = tid - 192;
  const int wIdx = isXyz ? ((tid / 12) * SROW + (tid % 12))
                         : ((t >> 2) * SROW + 12 + (t & 3));
  float4 v = isXyz ? q1[tid] : cohLoad4(rsg4 + t);
  float part = 0.f;
  for (int chunk = 0; chunk < 8; ++chunk) {
    lds_barrier();                  // prev compute's ds_reads done
    sStage4[wIdx] = v;              // auto-waits v (vmcnt dependency)
    if (chunk < 7) {
      v = isXyz ? q1[(chunk + 1) * 192 + tid]
                : cohLoad4(rsg4 + (chunk + 1) * 64 + t);
    }
    lds_barrier();                  // staged chunk visible; prefetch in flight
#pragma unroll
    for (int k = 0; k < 4; ++k) {
      float4 a  = sStage4[rowb + 3 * k];
      float4 bb = sStage4[rowb + 3 * k + 1];
      float4 cc = sStage4[rowb + 3 * k + 2];
      float4 r4 = sStage4[rowb + 12 + k];
      float px[4] = {a.x, a.w, bb.z, cc.y};
      float py[4] = {a.y, bb.x, bb.w, cc.z};
      float pz[4] = {a.z, bb.y, cc.x, cc.w};
      float rr[4] = {r4.x, r4.y, r4.z, r4.w};
#pragma unroll
      for (int j = 0; j < 4; ++j) {
        float dx = px[j] - pm.x, dy = py[j] - pm.y, dz = pz[j] - pm.z;
        float d2 = __builtin_fmaf(dx, dx, __builtin_fmaf(dy, dy, dz * dz));
        part = __builtin_fmaf(fast_exp2(nc * d2), rr[j], part);
      }
    }
  }
  part += __shfl_xor(part, 1, 64);
  part += __shfl_xor(part, 2, 64);
  part += __shfl_xor(part, 4, 64);
  part += __shfl_xor(part, 8, 64);
  if (c == 0) {
    float t1v = part;
    float rr = sRR[m_idx];
    float colsum = rr * t1v;
    float cs = fminf(rr / (colsum + 1e-9f), 1.0f);
    float ccv = rr * cs;
    float rn = fmaxf(rr - colsum * cs, 0.f);
    cohStore(wpB + t0 + m_idx, packh2(ccv, rn));
    sRR[m_idx] = rn;
  }
}

__global__ __launch_bounds__(BLOCK, 4) void emd_fused_kernel(
    const float* __restrict__ xyz1, const float* __restrict__ xyz2,
    float* __restrict__ out, float* __restrict__ rowscaleG,
    float* __restrict__ wPack, float* __restrict__ R9acc,
    float* __restrict__ t9, float* __restrict__ outAcc,
    unsigned* __restrict__ ctr) {
  __shared__ float4 sP[MPTS];          // raw x2,y2,z2; w = per-level payload
  __shared__ float4 sStage4[16 * SROW];// sweep2T chunk, padded rows
  __shared__ float sRedS[ROWS * 4];
  __shared__ float sRedC[ROWS * 4];
  __shared__ float sRedR[ROWS * 4];
  __shared__ float sCost[ROWS];
  __shared__ float sRowScale[ROWS];    // persistent across levels
  __shared__ float sRemainL[ROWS];     // persistent across levels
  __shared__ float sRR[ROWS];          // owner's rr slice, full precision

  const int tid = threadIdx.x;
  const int bid = blockIdx.x;
  const int b = bid >> 7;
  const int t0 = (bid & 127) * ROWS;
  const bool desig = (bid & 127) == 0;
  const int wave = tid >> 6, lane = tid & 63;
  const size_t bM = (size_t)b * MPTS;
  float costAcc = 0.f;                 // meaningful on tid==0

  float* rsG = rowscaleG + (size_t)b * NPTS;
  float* wpB = wPack + bM;
  const float4* q1 = (const float4*)(xyz1 + (size_t)b * NPTS * 3);
  const float4* q2 = (const float4*)(xyz2 + bM * 3);
#define CTRB(s) (ctr + (size_t)(((s) * BATCH + b) * NSUB) * PAD)

  // ---- init: stage raw xyz2; rr_0 = 1; zero scalar accumulators ----
  for (int g = tid; g < MPTS / 4; g += BLOCK) {
    float4 a = q2[3 * g], bb = q2[3 * g + 1], c = q2[3 * g + 2];
    sP[4 * g + 0] = make_float4(a.x, a.y, a.z, 0.f);
    sP[4 * g + 1] = make_float4(a.w, bb.x, bb.y, 0.f);
    sP[4 * g + 2] = make_float4(bb.z, bb.w, c.x, 0.f);
    sP[4 * g + 3] = make_float4(c.y, c.z, c.w, 0.f);
  }
  if (tid < ROWS) sRR[tid] = 1.0f;
  if (desig && tid == 0) {
    cohStore(R9acc + b * PAD, 0.f);
    cohStore(t9 + b * PAD, 0.f);
    cohStore(outAcc + b * PAD, 0.f);
  }
  __syncthreads();

  // ---- A0: rowscale_0 ----
  const float nc0 = -16384.0f * LOG2E;
  {
    const int ph = lane >> 1, rg = lane & 1;
    float x1a[8], y1a[8], z1a[8], acc[8];
    load8(q1, t0 + rg * 8, x1a, y1a, z1a);
#pragma unroll
    for (int j = 0; j < 8; ++j) acc[j] = 0.f;
    const int mb = wave * 512 + ph;
#pragma unroll 2
    for (int it = 0; it < 16; ++it) {
      float4 v = sP[mb + it * 32];
#pragma unroll
      for (int j = 0; j < 8; ++j) {
        float dx = x1a[j] - v.x, dy = y1a[j] - v.y, dz = z1a[j] - v.z;
        float d2 = __builtin_fmaf(dx, dx, __builtin_fmaf(dy, dy, dz * dz));
        acc[j] += fast_exp2(nc0 * d2);
      }
    }
#pragma unroll
    for (int j = 0; j < 8; ++j) {
      acc[j] += __shfl_xor(acc[j], 2, 64);
      acc[j] += __shfl_xor(acc[j], 4, 64);
      acc[j] += __shfl_xor(acc[j], 8, 64);
      acc[j] += __shfl_xor(acc[j], 16, 64);
      acc[j] += __shfl_xor(acc[j], 32, 64);
    }
    if (lane < 2) {
#pragma unroll
      for (int j = 0; j < 8; ++j) sRedS[(rg * 8 + j) * 4 + wave] = acc[j];
    }
    __syncthreads();
    if (tid < ROWS) {
      float s = sRedS[tid * 4] + sRedS[tid * 4 + 1] + sRedS[tid * 4 + 2] +
                sRedS[tid * 4 + 3];
      float rs = 1.0f / (s + 1e-9f);
      sRowScale[tid] = rs;
      cohStore(rsG + t0 + tid, rs);
    }
  }
  batch_barrier(CTRB(0), bid);          // rs_0 + init zeroes visible
  sweep2T_fuse(nc0, tid, t0, q1, rsG, wpB, sP, sStage4, sRR);  // -> wPack_0
  batch_barrier(CTRB(1), bid);          // wPack_0 visible

  // ---- persistent CA row fragment (raw coords) ----
  float x1[4], y1[4], z1[4];
  {
    int b4 = ((t0 + (lane & 3) * 4) >> 2) * 3;
    float4 a = q1[b4], bb = q1[b4 + 1], c = q1[b4 + 2];
    x1[0] = a.x;  y1[0] = a.y;  z1[0] = a.z;
    x1[1] = a.w;  y1[1] = bb.x; z1[1] = bb.y;
    x1[2] = bb.z; y1[2] = bb.w; z1[2] = c.x;
    x1[3] = c.y;  y1[3] = c.z;  z1[3] = c.w;
  }
  const int phc = lane >> 2, rgc = lane & 3;
  const int mbc = wave * 512 + phc;

  float nc2 = -4096.0f * LOG2E;   // levels[l+1]*LOG2E; exact /4 per level
  for (int l = 0; l < 9; ++l) {
    const bool LAST = (l == 8);
    // -- staging: sP[m].w = wPack_l[m], m = tid + 256k (8-way min; .w
    //    occupies only 8 of 32 banks). Coalesced coherent dword loads. --
#pragma unroll
    for (int k = 0; k < 8; ++k) {
      int m = tid + k * 256;
      sP[m].w = cohLoad(wpB + m);
    }
    __syncthreads();
    // -- sweep1: cost(l) + remainL + rowscale(l+1). e1 = e2^4 (exact). --
    float accS[4] = {0.f, 0.f, 0.f, 0.f};
    float accC[4] = {0.f, 0.f, 0.f, 0.f};
    float accR[4] = {0.f, 0.f, 0.f, 0.f};
#pragma unroll 4
    for (int it = 0; it < 32; ++it) {
      float4 v = sP[mbc + it * 16];
      __half2 h = __builtin_bit_cast(__half2, v.w);
      float cc = __low2float(h);
      float rr = __high2float(h);
#pragma unroll
      for (int j = 0; j < 4; ++j) {
        float dx = x1[j] - v.x, dy = y1[j] - v.y, dz = z1[j] - v.z;
        float d2 = __builtin_fmaf(dx, dx, __builtin_fmaf(dy, dy, dz * dz));
        float sq = fast_sqrt(d2);
        float e2 = fast_exp2(nc2 * d2);
        float e2s = e2 * e2;
        float e1 = e2s * e2s;   // exp(levels[l]*d2); at LAST -> exp(-0.25 d2)
        float t = e1 * cc;
        accS[j] += t;
        accC[j] = __builtin_fmaf(t, sq, accC[j]);
        accR[j] = __builtin_fmaf(e2, rr, accR[j]);
      }
    }
#pragma unroll
    for (int j = 0; j < 4; ++j) {
      accS[j] += __shfl_xor(accS[j], 4, 64);
      accS[j] += __shfl_xor(accS[j], 8, 64);
      accS[j] += __shfl_xor(accS[j], 16, 64);
      accS[j] += __shfl_xor(accS[j], 32, 64);
      accC[j] += __shfl_xor(accC[j], 4, 64);
      accC[j] += __shfl_xor(accC[j], 8, 64);
      accC[j] += __shfl_xor(accC[j], 16, 64);
      accC[j] += __shfl_xor(accC[j], 32, 64);
      accR[j] += __shfl_xor(accR[j], 4, 64);
      accR[j] += __shfl_xor(accR[j], 8, 64);
      accR[j] += __shfl_xor(accR[j], 16, 64);
      accR[j] += __shfl_xor(accR[j], 32, 64);
    }
    if (lane < 4) {
#pragma unroll
      for (int j = 0; j < 4; ++j) {
        sRedS[(rgc * 4 + j) * 4 + wave] = accS[j];
        sRedC[(rgc * 4 + j) * 4 + wave] = accC[j];
        sRedR[(rgc * 4 + j) * 4 + wave] = accR[j];
      }
    }
    __syncthreads();
    if (tid < ROWS) {
      float S2 = sRedS[tid * 4] + sRedS[tid * 4 + 1] + sRedS[tid * 4 + 2] +
                 sRedS[tid * 4 + 3];
      float C = sRedC[tid * 4] + sRedC[tid * 4 + 1] + sRedC[tid * 4 + 2] +
                sRedC[tid * 4 + 3];
      float R = sRedR[tid * 4] + sRedR[tid * 4 + 1] + sRedR[tid * 4 + 2] +
                sRedR[tid * 4 + 3];
      if (LAST) R = cohLoad(R9acc + b * PAD);   // sum_m rr_9 (e == 1)
      float rs = sRowScale[tid];
      float rl = (l == 0) ? 1.0f : sRemainL[tid];
      float rlN = fmaxf(rl - rs * S2, 0.f);
      sRemainL[tid] = rlN;
      float rsN = rlN / (R + 1e-9f);
      sRowScale[tid] = rsN;
      if (!LAST) cohStore(rsG + t0 + tid, rsN);
      sCost[tid] = rs * C;
    }
    __syncthreads();
    if (tid == 0) {
      float t = 0.f;
#pragma unroll
      for (int i = 0; i < ROWS; ++i) t += sCost[i];
      costAcc += t;
      if (LAST) {
        float r = 0.f;
#pragma unroll
        for (int i = 0; i < ROWS; ++i) r += sRowScale[i];
        atomicAdd(t9 + b * PAD, r);       // one per block, padded line
      }
    }
    if (!LAST) {
      batch_barrier(CTRB(2 + 2 * l), bid);    // rsN_{l+1} visible
      sweep2T_fuse(nc2, tid, t0, q1, rsG, wpB, sP, sStage4, sRR);
      if (l == 7) {          // R9 = sum_m rr_9: block partial, one atomic
        __syncthreads();
        if (tid == 0) {
          float r9 = 0.f;
#pragma unroll
          for (int i = 0; i < ROWS; ++i) r9 += sRR[i];
          atomicAdd(R9acc + b * PAD, r9);
        }
      }
      batch_barrier(CTRB(3 + 2 * l), bid);    // wPack_{l+1} (+R9acc) visible
      nc2 *= 0.25f;
    }
  }
  batch_barrier(CTRB(18), bid);               // t9 complete

  // ---- C9 owner publish: w[m] from full-precision rr_9 + t9 ----
  if (tid < ROWS) {
    float rr = sRR[tid];
    float t1s = cohLoad(t9 + b * PAD);
    float w = rr * fminf(rr / (__builtin_fmaf(rr, t1s, 1e-9f)), 1.0f);
    cohStore(wpB + t0 + tid, w);              // full float (matches old C9)
  }
  batch_barrier(CTRB(19), bid);               // w visible

  // ---- C9 (lvl=0): cost with unscaled coords ----
  {
#pragma unroll
    for (int k = 0; k < 8; ++k) {
      int m = tid + k * 256;
      sP[m].w = cohLoad(wpB + m);
    }
    __syncthreads();
    const int ph = lane >> 1, rg = lane & 1;
    float x1a[8], y1a[8], z1a[8], acc[8];
    load8(q1, t0 + rg * 8, x1a, y1a, z1a);
#pragma unroll
    for (int j = 0; j < 8; ++j) acc[j] = 0.f;
    const int mb = wave * 512 + ph;
#pragma unroll 2
    for (int it = 0; it < 16; ++it) {
      float4 v = sP[mb + it * 32];
#pragma unroll
      for (int j = 0; j < 8; ++j) {
        float dx = x1a[j] - v.x, dy = y1a[j] - v.y, dz = z1a[j] - v.z;
        float d2 = __builtin_fmaf(dx, dx, __builtin_fmaf(dy, dy, dz * dz));
        acc[j] = __builtin_fmaf(fast_sqrt(d2), v.w, acc[j]);
      }
    }
#pragma unroll
    for (int j = 0; j < 8; ++j) {
      acc[j] += __shfl_xor(acc[j], 2, 64);
      acc[j] += __shfl_xor(acc[j], 4, 64);
      acc[j] += __shfl_xor(acc[j], 8, 64);
      acc[j] += __shfl_xor(acc[j], 16, 64);
      acc[j] += __shfl_xor(acc[j], 32, 64);
    }
    if (lane < 2) {
#pragma unroll
      for (int j = 0; j < 8; ++j) sRedS[(rg * 8 + j) * 4 + wave] = acc[j];
    }
    __syncthreads();
    if (tid < ROWS) {
      float C = sRedS[tid * 4] + sRedS[tid * 4 + 1] + sRedS[tid * 4 + 2] +
                sRedS[tid * 4 + 3];
      sCost[tid] = sRowScale[tid] * C;
    }
    __syncthreads();
    if (tid == 0) {
      float t = 0.f;
#pragma unroll
      for (int i = 0; i < ROWS; ++i) t += sCost[i];
      costAcc += t;
      atomicAdd(outAcc + b * PAD, costAcc);   // ONE atomic per block total
    }
  }
  batch_barrier(CTRB(20), bid);               // outAcc complete
  if (desig && tid == 0) out[b] = cohLoad(outAcc + b * PAD);
#undef CTRB
}

// ---------------------------------------------------------------------------
extern "C" void kernel_launch(void* const* d_in, const int* in_sizes, int n_in,
                              void* d_out, int out_size, void* d_ws, size_t ws_size,
                              hipStream_t stream) {
  const float* xyz1 = (const float*)d_in[0];
  const float* xyz2 = (const float*)d_in[1];
  float* out = (float*)d_out;
  float* ws = (float*)d_ws;

  const int BM = BATCH * MPTS;               // 16384
  float* rowscaleG = ws;                     // BM
  float* wPack     = ws + BM;                // BM
  float* R9acc     = ws + 2 * BM;            // BATCH*PAD
  float* t9        = ws + 2 * BM + BATCH * PAD;      // BATCH*PAD
  float* outAcc    = ws + 2 * BM + 2 * BATCH * PAD;  // BATCH*PAD
  unsigned* ctr    = (unsigned*)(ws + 2 * BM + 3 * BATCH * PAD);
  // ctr: NSYNC*BATCH*NSUB*PAD u32 = 21*8*8*16 = 21504 u32 (~86KB)

  hipMemsetAsync(ctr, 0, (size_t)NSYNC * BATCH * NSUB * PAD * sizeof(unsigned),
                 stream);

  void* args[] = {(void*)&xyz1, (void*)&xyz2, (void*)&out, (void*)&rowscaleG,
                  (void*)&wPack, (void*)&R9acc, (void*)&t9, (void*)&outAcc,
                  (void*)&ctr};
  hipLaunchKernel((const void*)emd_fused_kernel,
                  dim3(BATCH * (NPTS / ROWS)), dim3(BLOCK), args, 0, stream);
}

// Round 8
// 314.559 us; speedup vs baseline: 2.4509x; 1.2016x over previous
//
#include <hip/hip_runtime.h>
#include <hip/hip_fp16.h>

// EMD approx-match (auction) + match_cost, fully fused, ONE normal launch.
// R22: R21 = 343us fused, VALUBusy 65%, conflicts fixed (6.8e7->4.4e6). The
// ~115us residual stall is barrier-frequency-bound: identical per-batch work
// keeps co-resident blocks in lockstep, so every barrier idles whole CUs
// (skew + detect ~= 4-5us x 21). This round halves barrier frequency:
// 512 blocks x 512 threads (64 blocks/batch, 32 rows/block) -- same total
// VALU work, same 21 barriers, but each phase is 2x longer and arrive
// chains halve (8/line). waves/CU unchanged (2 blocks x 8 waves = 16).
// sweep2T now stages 2 chunks/round into double-buffered padded LDS rows
// (4 rounds, tid<256 -> bufA chunk 2r, tid>=256 -> bufB chunk 2r+1),
// register prefetch + lgkm-only barriers preserved (8 per call, was 16).
// Geometry: wave -> (m-quadrant = wave&3, row-half = wave>>2).

#define BATCH 8
#define NPTS 2048
#define MPTS 2048
#define BLOCK 512
#define ROWS 32
#define BLOCKS_PER_BATCH 64
#define NSUB 8
#define SUBTGT (BLOCKS_PER_BATCH / NSUB)   // 8
#define NSYNC 21
#define PAD 16                             // dwords per 64B line
#define SROW 17                            // padded staging row, float4s
#define LOG2E 1.44269504088896340736f

__device__ __forceinline__ float fast_exp2(float x) {
  return __builtin_amdgcn_exp2f(x);     // v_exp_f32
}
__device__ __forceinline__ float fast_sqrt(float a) {
  return __builtin_amdgcn_sqrtf(a);     // v_sqrt_f32
}
__device__ __forceinline__ float packh2(float c, float r) {
  __half2 h = __halves2half2(__float2half_rn(c), __float2half_rn(r));
  return __builtin_bit_cast(float, h);
}

// ---- agent-scope coherent access helpers (bypass non-coherent XCD L2) ----
__device__ __forceinline__ float cohLoad(const float* p) {
  return __hip_atomic_load((float*)p, __ATOMIC_RELAXED,
                           __HIP_MEMORY_SCOPE_AGENT);
}
__device__ __forceinline__ void cohStore(float* p, float v) {
  __hip_atomic_store(p, v, __ATOMIC_RELAXED, __HIP_MEMORY_SCOPE_AGENT);
}
__device__ __forceinline__ float4 cohLoad4(const float4* p) {
  const float* f = (const float*)p;
  return make_float4(cohLoad(f), cohLoad(f + 1), cohLoad(f + 2),
                     cohLoad(f + 3));
}

// LDS-only barrier: waits DS ops (lgkm) but leaves global/coherent loads
// (vmcnt) in flight. sched_barrier(0) pins hipcc from hoisting past it.
__device__ __forceinline__ void lds_barrier() {
  asm volatile("s_waitcnt lgkmcnt(0)" ::: "memory");
  __builtin_amdgcn_s_barrier();
  __builtin_amdgcn_sched_barrier(0);
}

// Per-batch grid barrier, two-level: 8 sub-counters (own 64B line each),
// 8 arrivals per sub. Absolute target (counters memset each launch).
// __syncthreads before arrive drains vmcnt(0) per wave -> all block
// writes/atomics complete at the coherent point before the arrive.
__device__ __forceinline__ void batch_barrier(unsigned* base, int bid) {
  __syncthreads();
  if (threadIdx.x == 0) {
    __hip_atomic_fetch_add(base + (bid & (NSUB - 1)) * PAD, 1u,
                           __ATOMIC_RELAXED, __HIP_MEMORY_SCOPE_AGENT);
  }
  if (threadIdx.x < NSUB) {
    int guard = 0;
    while (__hip_atomic_load(base + threadIdx.x * PAD, __ATOMIC_RELAXED,
                             __HIP_MEMORY_SCOPE_AGENT) < (unsigned)SUBTGT) {
      __builtin_amdgcn_s_sleep(2);
      if (++guard > (1 << 22)) break;
    }
  }
  asm volatile("" ::: "memory");
  __syncthreads();
}

// Load 8 consecutive points (r0 multiple of 8) as 6 float4s (raw).
__device__ __forceinline__ void load8(const float4* q, int r0,
                                      float* x, float* y, float* z) {
  int b4 = (r0 >> 2) * 3;
  float4 q0 = q[b4], q1 = q[b4 + 1], q2 = q[b4 + 2];
  float4 q3 = q[b4 + 3], q4 = q[b4 + 4], q5 = q[b4 + 5];
  x[0] = q0.x; y[0] = q0.y; z[0] = q0.z;
  x[1] = q0.w; y[1] = q1.x; z[1] = q1.y;
  x[2] = q1.z; y[2] = q1.w; z[2] = q2.x;
  x[3] = q2.y; y[3] = q2.z; z[3] = q2.w;
  x[4] = q3.x; y[4] = q3.y; z[4] = q3.z;
  x[5] = q3.w; y[5] = q4.x; z[5] = q4.y;
  x[6] = q4.z; y[6] = q4.w; z[6] = q5.x;
  x[7] = q5.y; y[7] = q5.z; z[7] = q5.w;
}

// Transposed t1 sweep + owner fusion, 512 threads. Thread t: m_idx = t>>4
// (owned m = t0+m_idx, 32 per block), c = t&15 covers points [c*16,c*16+16)
// of each 256-n chunk. 2 chunks staged per round into double-buffered
// padded rows: tid<256 -> bufA (chunk 2r), tid>=256 -> bufB (chunk 2r+1).
// Register prefetch; lgkm-only barriers keep prefetch loads in flight.
__device__ __forceinline__ void sweep2T_fuse(
    float nc, int tid, int t0, const float4* q1, const float* rsG,
    float* wpB, const float4* sP, float4* sStage, float* sRR) {
  const int m_idx = tid >> 4, c = tid & 15;
  const float4 pm = sP[t0 + m_idx];
  const float4* rsg4 = (const float4*)rsG;
  const int rowb = c * SROW;
  const int tl = tid & 255;
  const int half = tid >> 8;            // 0 -> chunk 2r, 1 -> chunk 2r+1
  const bool isXyz = tl < 192;
  const int t = tl - 192;
  const int wIdx = half * (16 * SROW) +
                   (isXyz ? ((tl / 12) * SROW + (tl % 12))
                          : ((t >> 2) * SROW + 12 + (t & 3)));
  float4 v = isXyz ? q1[half * 192 + tl] : cohLoad4(rsg4 + half * 64 + t);
  float part = 0.f;
  for (int r = 0; r < 4; ++r) {
    lds_barrier();                  // prev round's ds_reads done
    sStage[wIdx] = v;               // auto-waits v (vmcnt dependency)
    if (r < 3) {
      int ch = 2 * (r + 1) + half;
      v = isXyz ? q1[ch * 192 + tl] : cohLoad4(rsg4 + ch * 64 + t);
    }
    lds_barrier();                  // staged pair visible; prefetch in flight
#pragma unroll
    for (int h = 0; h < 2; ++h) {
      const float4* sB = sStage + h * (16 * SROW);
#pragma unroll
      for (int k = 0; k < 4; ++k) {
        float4 a  = sB[rowb + 3 * k];
        float4 bb = sB[rowb + 3 * k + 1];
        float4 cc = sB[rowb + 3 * k + 2];
        float4 r4 = sB[rowb + 12 + k];
        float px[4] = {a.x, a.w, bb.z, cc.y};
        float py[4] = {a.y, bb.x, bb.w, cc.z};
        float pz[4] = {a.z, bb.y, cc.x, cc.w};
        float rr[4] = {r4.x, r4.y, r4.z, r4.w};
#pragma unroll
        for (int j = 0; j < 4; ++j) {
          float dx = px[j] - pm.x, dy = py[j] - pm.y, dz = pz[j] - pm.z;
          float d2 = __builtin_fmaf(dx, dx, __builtin_fmaf(dy, dy, dz * dz));
          part = __builtin_fmaf(fast_exp2(nc * d2), rr[j], part);
        }
      }
    }
  }
  part += __shfl_xor(part, 1, 64);
  part += __shfl_xor(part, 2, 64);
  part += __shfl_xor(part, 4, 64);
  part += __shfl_xor(part, 8, 64);
  if (c == 0) {
    float t1v = part;
    float rr = sRR[m_idx];
    float colsum = rr * t1v;
    float cs = fminf(rr / (colsum + 1e-9f), 1.0f);
    float ccv = rr * cs;
    float rn = fmaxf(rr - colsum * cs, 0.f);
    cohStore(wpB + t0 + m_idx, packh2(ccv, rn));
    sRR[m_idx] = rn;
  }
}

__global__ __launch_bounds__(BLOCK, 4) void emd_fused_kernel(
    const float* __restrict__ xyz1, const float* __restrict__ xyz2,
    float* __restrict__ out, float* __restrict__ rowscaleG,
    float* __restrict__ wPack, float* __restrict__ R9acc,
    float* __restrict__ t9, float* __restrict__ outAcc,
    unsigned* __restrict__ ctr) {
  __shared__ float4 sP[MPTS];            // raw x2,y2,z2; w = level payload
  __shared__ float4 sStage[2 * 16 * SROW]; // sweep2T double buffer
  __shared__ float sRedS[ROWS * 4];
  __shared__ float sRedC[ROWS * 4];
  __shared__ float sRedR[ROWS * 4];
  __shared__ float sCost[ROWS];
  __shared__ float sRowScale[ROWS];      // persistent across levels
  __shared__ float sRemainL[ROWS];       // persistent across levels
  __shared__ float sRR[ROWS];            // owner's rr slice, full precision

  const int tid = threadIdx.x;
  const int bid = blockIdx.x;
  const int b = bid >> 6;
  const int t0 = (bid & 63) * ROWS;
  const bool desig = (bid & 63) == 0;
  const int wave = tid >> 6, lane = tid & 63;
  const int mq = wave & 3;               // m-quadrant
  const int rh = wave >> 2;              // row-half (0/1)
  const size_t bM = (size_t)b * MPTS;
  float costAcc = 0.f;                   // meaningful on tid==0

  float* rsG = rowscaleG + (size_t)b * NPTS;
  float* wpB = wPack + bM;
  const float4* q1 = (const float4*)(xyz1 + (size_t)b * NPTS * 3);
  const float4* q2 = (const float4*)(xyz2 + bM * 3);
#define CTRB(s) (ctr + (size_t)(((s) * BATCH + b) * NSUB) * PAD)

  // ---- init: stage raw xyz2; rr_0 = 1; zero scalar accumulators ----
  {
    int g = tid;                         // MPTS/4 == BLOCK
    float4 a = q2[3 * g], bb = q2[3 * g + 1], c = q2[3 * g + 2];
    sP[4 * g + 0] = make_float4(a.x, a.y, a.z, 0.f);
    sP[4 * g + 1] = make_float4(a.w, bb.x, bb.y, 0.f);
    sP[4 * g + 2] = make_float4(bb.z, bb.w, c.x, 0.f);
    sP[4 * g + 3] = make_float4(c.y, c.z, c.w, 0.f);
  }
  if (tid < ROWS) sRR[tid] = 1.0f;
  if (desig && tid == 0) {
    cohStore(R9acc + b * PAD, 0.f);
    cohStore(t9 + b * PAD, 0.f);
    cohStore(outAcc + b * PAD, 0.f);
  }
  __syncthreads();

  // ---- A0: rowscale_0 ----
  const float nc0 = -16384.0f * LOG2E;
  {
    const int ph = lane >> 1, rg = lane & 1;
    float x1a[8], y1a[8], z1a[8], acc[8];
    load8(q1, t0 + rh * 16 + rg * 8, x1a, y1a, z1a);
#pragma unroll
    for (int j = 0; j < 8; ++j) acc[j] = 0.f;
    const int mb = mq * 512 + ph;
#pragma unroll 2
    for (int it = 0; it < 16; ++it) {
      float4 v = sP[mb + it * 32];
#pragma unroll
      for (int j = 0; j < 8; ++j) {
        float dx = x1a[j] - v.x, dy = y1a[j] - v.y, dz = z1a[j] - v.z;
        float d2 = __builtin_fmaf(dx, dx, __builtin_fmaf(dy, dy, dz * dz));
        acc[j] += fast_exp2(nc0 * d2);
      }
    }
#pragma unroll
    for (int j = 0; j < 8; ++j) {
      acc[j] += __shfl_xor(acc[j], 2, 64);
      acc[j] += __shfl_xor(acc[j], 4, 64);
      acc[j] += __shfl_xor(acc[j], 8, 64);
      acc[j] += __shfl_xor(acc[j], 16, 64);
      acc[j] += __shfl_xor(acc[j], 32, 64);
    }
    if (lane < 2) {
#pragma unroll
      for (int j = 0; j < 8; ++j)
        sRedS[(rh * 16 + rg * 8 + j) * 4 + mq] = acc[j];
    }
    __syncthreads();
    if (tid < ROWS) {
      float s = sRedS[tid * 4] + sRedS[tid * 4 + 1] + sRedS[tid * 4 + 2] +
                sRedS[tid * 4 + 3];
      float rs = 1.0f / (s + 1e-9f);
      sRowScale[tid] = rs;
      cohStore(rsG + t0 + tid, rs);
    }
  }
  batch_barrier(CTRB(0), bid);          // rs_0 + init zeroes visible
  sweep2T_fuse(nc0, tid, t0, q1, rsG, wpB, sP, sStage, sRR);   // -> wPack_0
  batch_barrier(CTRB(1), bid);          // wPack_0 visible

  // ---- persistent CA row fragment (raw coords) ----
  float x1[4], y1[4], z1[4];
  {
    int b4 = ((t0 + rh * 16 + (lane & 3) * 4) >> 2) * 3;
    float4 a = q1[b4], bb = q1[b4 + 1], c = q1[b4 + 2];
    x1[0] = a.x;  y1[0] = a.y;  z1[0] = a.z;
    x1[1] = a.w;  y1[1] = bb.x; z1[1] = bb.y;
    x1[2] = bb.z; y1[2] = bb.w; z1[2] = c.x;
    x1[3] = c.y;  y1[3] = c.z;  z1[3] = c.w;
  }
  const int phc = lane >> 2, rgc = lane & 3;
  const int mbc = mq * 512 + phc;

  float nc2 = -4096.0f * LOG2E;   // levels[l+1]*LOG2E; exact /4 per level
  for (int l = 0; l < 9; ++l) {
    const bool LAST = (l == 8);
    // -- staging: sP[m].w = wPack_l[m], m = tid + 512k --
#pragma unroll
    for (int k = 0; k < 4; ++k) {
      int m = tid + k * 512;
      sP[m].w = cohLoad(wpB + m);
    }
    __syncthreads();
    // -- sweep1: cost(l) + remainL + rowscale(l+1). e1 = e2^4 (exact). --
    float accS[4] = {0.f, 0.f, 0.f, 0.f};
    float accC[4] = {0.f, 0.f, 0.f, 0.f};
    float accR[4] = {0.f, 0.f, 0.f, 0.f};
#pragma unroll 4
    for (int it = 0; it < 32; ++it) {
      float4 v = sP[mbc + it * 16];
      __half2 h = __builtin_bit_cast(__half2, v.w);
      float cc = __low2float(h);
      float rr = __high2float(h);
#pragma unroll
      for (int j = 0; j < 4; ++j) {
        float dx = x1[j] - v.x, dy = y1[j] - v.y, dz = z1[j] - v.z;
        float d2 = __builtin_fmaf(dx, dx, __builtin_fmaf(dy, dy, dz * dz));
        float sq = fast_sqrt(d2);
        float e2 = fast_exp2(nc2 * d2);
        float e2s = e2 * e2;
        float e1 = e2s * e2s;   // exp(levels[l]*d2); at LAST -> exp(-0.25 d2)
        float t = e1 * cc;
        accS[j] += t;
        accC[j] = __builtin_fmaf(t, sq, accC[j]);
        accR[j] = __builtin_fmaf(e2, rr, accR[j]);
      }
    }
#pragma unroll
    for (int j = 0; j < 4; ++j) {
      accS[j] += __shfl_xor(accS[j], 4, 64);
      accS[j] += __shfl_xor(accS[j], 8, 64);
      accS[j] += __shfl_xor(accS[j], 16, 64);
      accS[j] += __shfl_xor(accS[j], 32, 64);
      accC[j] += __shfl_xor(accC[j], 4, 64);
      accC[j] += __shfl_xor(accC[j], 8, 64);
      accC[j] += __shfl_xor(accC[j], 16, 64);
      accC[j] += __shfl_xor(accC[j], 32, 64);
      accR[j] += __shfl_xor(accR[j], 4, 64);
      accR[j] += __shfl_xor(accR[j], 8, 64);
      accR[j] += __shfl_xor(accR[j], 16, 64);
      accR[j] += __shfl_xor(accR[j], 32, 64);
    }
    if (lane < 4) {
#pragma unroll
      for (int j = 0; j < 4; ++j) {
        int row = rh * 16 + rgc * 4 + j;   // rgc == lane here
        sRedS[row * 4 + mq] = accS[j];
        sRedC[row * 4 + mq] = accC[j];
        sRedR[row * 4 + mq] = accR[j];
      }
    }
    __syncthreads();
    if (tid < ROWS) {
      float S2 = sRedS[tid * 4] + sRedS[tid * 4 + 1] + sRedS[tid * 4 + 2] +
                 sRedS[tid * 4 + 3];
      float C = sRedC[tid * 4] + sRedC[tid * 4 + 1] + sRedC[tid * 4 + 2] +
                sRedC[tid * 4 + 3];
      float R = sRedR[tid * 4] + sRedR[tid * 4 + 1] + sRedR[tid * 4 + 2] +
                sRedR[tid * 4 + 3];
      if (LAST) R = cohLoad(R9acc + b * PAD);   // sum_m rr_9 (e == 1)
      float rs = sRowScale[tid];
      float rl = (l == 0) ? 1.0f : sRemainL[tid];
      float rlN = fmaxf(rl - rs * S2, 0.f);
      sRemainL[tid] = rlN;
      float rsN = rlN / (R + 1e-9f);
      sRowScale[tid] = rsN;
      if (!LAST) cohStore(rsG + t0 + tid, rsN);
      sCost[tid] = rs * C;
    }
    __syncthreads();
    if (tid == 0) {
      float t = 0.f;
#pragma unroll
      for (int i = 0; i < ROWS; ++i) t += sCost[i];
      costAcc += t;
      if (LAST) {
        float r = 0.f;
#pragma unroll
        for (int i = 0; i < ROWS; ++i) r += sRowScale[i];
        atomicAdd(t9 + b * PAD, r);       // one per block, padded line
      }
    }
    if (!LAST) {
      batch_barrier(CTRB(2 + 2 * l), bid);    // rsN_{l+1} visible
      sweep2T_fuse(nc2, tid, t0, q1, rsG, wpB, sP, sStage, sRR);
      if (l == 7) {          // R9 = sum_m rr_9: block partial, one atomic
        __syncthreads();
        if (tid == 0) {
          float r9 = 0.f;
#pragma unroll
          for (int i = 0; i < ROWS; ++i) r9 += sRR[i];
          atomicAdd(R9acc + b * PAD, r9);
        }
      }
      batch_barrier(CTRB(3 + 2 * l), bid);    // wPack_{l+1} (+R9acc) visible
      nc2 *= 0.25f;
    }
  }
  batch_barrier(CTRB(18), bid);               // t9 complete

  // ---- C9 owner publish: w[m] from full-precision rr_9 + t9 ----
  if (tid < ROWS) {
    float rr = sRR[tid];
    float t1s = cohLoad(t9 + b * PAD);
    float w = rr * fminf(rr / (__builtin_fmaf(rr, t1s, 1e-9f)), 1.0f);
    cohStore(wpB + t0 + tid, w);              // full float (matches old C9)
  }
  batch_barrier(CTRB(19), bid);               // w visible

  // ---- C9 (lvl=0): cost with unscaled coords ----
  {
#pragma unroll
    for (int k = 0; k < 4; ++k) {
      int m = tid + k * 512;
      sP[m].w = cohLoad(wpB + m);
    }
    __syncthreads();
    const int ph = lane >> 1, rg = lane & 1;
    float x1a[8], y1a[8], z1a[8], acc[8];
    load8(q1, t0 + rh * 16 + rg * 8, x1a, y1a, z1a);
#pragma unroll
    for (int j = 0; j < 8; ++j) acc[j] = 0.f;
    const int mb = mq * 512 + ph;
#pragma unroll 2
    for (int it = 0; it < 16; ++it) {
      float4 v = sP[mb + it * 32];
#pragma unroll
      for (int j = 0; j < 8; ++j) {
        float dx = x1a[j] - v.x, dy = y1a[j] - v.y, dz = z1a[j] - v.z;
        float d2 = __builtin_fmaf(dx, dx, __builtin_fmaf(dy, dy, dz * dz));
        acc[j] = __builtin_fmaf(fast_sqrt(d2), v.w, acc[j]);
      }
    }
#pragma unroll
    for (int j = 0; j < 8; ++j) {
      acc[j] += __shfl_xor(acc[j], 2, 64);
      acc[j] += __shfl_xor(acc[j], 4, 64);
      acc[j] += __shfl_xor(acc[j], 8, 64);
      acc[j] += __shfl_xor(acc[j], 16, 64);
      acc[j] += __shfl_xor(acc[j], 32, 64);
    }
    if (lane < 2) {
#pragma unroll
      for (int j = 0; j < 8; ++j)
        sRedS[(rh * 16 + rg * 8 + j) * 4 + mq] = acc[j];
    }
    __syncthreads();
    if (tid < ROWS) {
      float C = sRedS[tid * 4] + sRedS[tid * 4 + 1] + sRedS[tid * 4 + 2] +
                sRedS[tid * 4 + 3];
      sCost[tid] = sRowScale[tid] * C;
    }
    __syncthreads();
    if (tid == 0) {
      float t = 0.f;
#pragma unroll
      for (int i = 0; i < ROWS; ++i) t += sCost[i];
      costAcc += t;
      atomicAdd(outAcc + b * PAD, costAcc);   // ONE atomic per block total
    }
  }
  batch_barrier(CTRB(20), bid);               // outAcc complete
  if (desig && tid == 0) out[b] = cohLoad(outAcc + b * PAD);
#undef CTRB
}

// ---------------------------------------------------------------------------
extern "C" void kernel_launch(void* const* d_in, const int* in_sizes, int n_in,
                              void* d_out, int out_size, void* d_ws, size_t ws_size,
                              hipStream_t stream) {
  const float* xyz1 = (const float*)d_in[0];
  const float* xyz2 = (const float*)d_in[1];
  float* out = (float*)d_out;
  float* ws = (float*)d_ws;

  const int BM = BATCH * MPTS;               // 16384
  float* rowscaleG = ws;                     // BM
  float* wPack     = ws + BM;                // BM
  float* R9acc     = ws + 2 * BM;            // BATCH*PAD
  float* t9        = ws + 2 * BM + BATCH * PAD;      // BATCH*PAD
  float* outAcc    = ws + 2 * BM + 2 * BATCH * PAD;  // BATCH*PAD
  unsigned* ctr    = (unsigned*)(ws + 2 * BM + 3 * BATCH * PAD);
  // ctr: NSYNC*BATCH*NSUB*PAD u32 = 21*8*8*16 = 21504 u32 (~86KB)

  hipMemsetAsync(ctr, 0, (size_t)NSYNC * BATCH * NSUB * PAD * sizeof(unsigned),
                 stream);

  void* args[] = {(void*)&xyz1, (void*)&xyz2, (void*)&out, (void*)&rowscaleG,
                  (void*)&wPack, (void*)&R9acc, (void*)&t9, (void*)&outAcc,
                  (void*)&ctr};
  hipLaunchKernel((const void*)emd_fused_kernel,
                  dim3(BATCH * (NPTS / ROWS)), dim3(BLOCK), args, 0, stream);
}

// Round 9
// 312.530 us; speedup vs baseline: 2.4668x; 1.0065x over previous
//
#include <hip/hip_runtime.h>
#include <hip/hip_fp16.h>

// EMD approx-match (auction) + match_cost, fully fused, ONE normal launch.
// R23: R22 (289us fused, VALUBusy 78%, total 314.6 -- first beat of the
// 357us dispatch baseline) confirmed the barrier-frequency/skew model
// (phase-doubling converted ~54us stall into compute). Floor: ~225us VALU
// issue (~90us of it trans-pipe: 30 exp/sqrt per pair, structural). This
// round halves barrier frequency AGAIN: 256 blocks x 1024 threads
// (32 blocks/batch, 64 rows/block) -- grid == CU count exactly, one block
// per CU (uniform placement; R22's 39% occupancy suggested uneven 2-3
// packing), arrive chains 4/sub-line, same 21 barriers over 2x phases.
// TLP unchanged (16 waves/CU). sweep2T: 4 chunks/round staged by the four
// 256-thread quarters into 4 padded buffers, 2 rounds, register prefetch +
// lgkm-only barriers preserved. Geometry: wave -> (mq = wave&3 m-quadrant,
// rh = wave>>2 row-quarter of 64 rows). LDS ~54KB.

#define BATCH 8
#define NPTS 2048
#define MPTS 2048
#define BLOCK 1024
#define ROWS 64
#define BLOCKS_PER_BATCH 32
#define NSUB 8
#define SUBTGT (BLOCKS_PER_BATCH / NSUB)   // 4
#define NSYNC 21
#define PAD 16                             // dwords per 64B line
#define SROW 17                            // padded staging row, float4s
#define LOG2E 1.44269504088896340736f

__device__ __forceinline__ float fast_exp2(float x) {
  return __builtin_amdgcn_exp2f(x);     // v_exp_f32
}
__device__ __forceinline__ float fast_sqrt(float a) {
  return __builtin_amdgcn_sqrtf(a);     // v_sqrt_f32
}
__device__ __forceinline__ float packh2(float c, float r) {
  __half2 h = __halves2half2(__float2half_rn(c), __float2half_rn(r));
  return __builtin_bit_cast(float, h);
}

// ---- agent-scope coherent access helpers (bypass non-coherent XCD L2) ----
__device__ __forceinline__ float cohLoad(const float* p) {
  return __hip_atomic_load((float*)p, __ATOMIC_RELAXED,
                           __HIP_MEMORY_SCOPE_AGENT);
}
__device__ __forceinline__ void cohStore(float* p, float v) {
  __hip_atomic_store(p, v, __ATOMIC_RELAXED, __HIP_MEMORY_SCOPE_AGENT);
}
__device__ __forceinline__ float4 cohLoad4(const float4* p) {
  const float* f = (const float*)p;
  return make_float4(cohLoad(f), cohLoad(f + 1), cohLoad(f + 2),
                     cohLoad(f + 3));
}

// LDS-only barrier: waits DS ops (lgkm) but leaves global/coherent loads
// (vmcnt) in flight. sched_barrier(0) pins hipcc from hoisting past it.
__device__ __forceinline__ void lds_barrier() {
  asm volatile("s_waitcnt lgkmcnt(0)" ::: "memory");
  __builtin_amdgcn_s_barrier();
  __builtin_amdgcn_sched_barrier(0);
}

// Per-batch grid barrier, two-level: 8 sub-counters (own 64B line each),
// 4 arrivals per sub. Absolute target (counters memset each launch).
// __syncthreads before arrive drains vmcnt(0) per wave -> all block
// writes/atomics complete at the coherent point before the arrive.
__device__ __forceinline__ void batch_barrier(unsigned* base, int bid) {
  __syncthreads();
  if (threadIdx.x == 0) {
    __hip_atomic_fetch_add(base + (bid & (NSUB - 1)) * PAD, 1u,
                           __ATOMIC_RELAXED, __HIP_MEMORY_SCOPE_AGENT);
  }
  if (threadIdx.x < NSUB) {
    int guard = 0;
    while (__hip_atomic_load(base + threadIdx.x * PAD, __ATOMIC_RELAXED,
                             __HIP_MEMORY_SCOPE_AGENT) < (unsigned)SUBTGT) {
      __builtin_amdgcn_s_sleep(2);
      if (++guard > (1 << 22)) break;
    }
  }
  asm volatile("" ::: "memory");
  __syncthreads();
}

// Load 8 consecutive points (r0 multiple of 8) as 6 float4s (raw).
__device__ __forceinline__ void load8(const float4* q, int r0,
                                      float* x, float* y, float* z) {
  int b4 = (r0 >> 2) * 3;
  float4 q0 = q[b4], q1 = q[b4 + 1], q2 = q[b4 + 2];
  float4 q3 = q[b4 + 3], q4 = q[b4 + 4], q5 = q[b4 + 5];
  x[0] = q0.x; y[0] = q0.y; z[0] = q0.z;
  x[1] = q0.w; y[1] = q1.x; z[1] = q1.y;
  x[2] = q1.z; y[2] = q1.w; z[2] = q2.x;
  x[3] = q2.y; y[3] = q2.z; z[3] = q2.w;
  x[4] = q3.x; y[4] = q3.y; z[4] = q3.z;
  x[5] = q3.w; y[5] = q4.x; z[5] = q4.y;
  x[6] = q4.z; y[6] = q4.w; z[6] = q5.x;
  x[7] = q5.y; y[7] = q5.z; z[7] = q5.w;
}

// Transposed t1 sweep + owner fusion, 1024 threads. Thread t: m_idx = t>>4
// (owned m = t0+m_idx, 64 per block), c = t&15 covers points [c*16,c*16+16)
// of each 256-n chunk. 4 chunks staged per round into 4 padded buffers:
// quarter q = tid>>8 stages chunk 4r+q. 2 rounds. Register prefetch;
// lgkm-only barriers keep prefetch loads in flight.
__device__ __forceinline__ void sweep2T_fuse(
    float nc, int tid, int t0, const float4* q1, const float* rsG,
    float* wpB, const float4* sP, float4* sStage, float* sRR) {
  const int m_idx = tid >> 4, c = tid & 15;
  const float4 pm = sP[t0 + m_idx];
  const float4* rsg4 = (const float4*)rsG;
  const int rowb = c * SROW;
  const int tl = tid & 255;
  const int qtr = tid >> 8;            // quarter stages chunk 4r+qtr
  const bool isXyz = tl < 192;
  const int t = tl - 192;
  const int wIdx = qtr * (16 * SROW) +
                   (isXyz ? ((tl / 12) * SROW + (tl % 12))
                          : ((t >> 2) * SROW + 12 + (t & 3)));
  float4 v = isXyz ? q1[qtr * 192 + tl] : cohLoad4(rsg4 + qtr * 64 + t);
  float part = 0.f;
  for (int r = 0; r < 2; ++r) {
    lds_barrier();                  // prev round's ds_reads done
    sStage[wIdx] = v;               // auto-waits v (vmcnt dependency)
    if (r < 1) {
      int ch = 4 + qtr;
      v = isXyz ? q1[ch * 192 + tl] : cohLoad4(rsg4 + ch * 64 + t);
    }
    lds_barrier();                  // staged quad visible; prefetch in flight
#pragma unroll
    for (int h = 0; h < 4; ++h) {
      const float4* sB = sStage + h * (16 * SROW);
#pragma unroll
      for (int k = 0; k < 4; ++k) {
        float4 a  = sB[rowb + 3 * k];
        float4 bb = sB[rowb + 3 * k + 1];
        float4 cc = sB[rowb + 3 * k + 2];
        float4 r4 = sB[rowb + 12 + k];
        float px[4] = {a.x, a.w, bb.z, cc.y};
        float py[4] = {a.y, bb.x, bb.w, cc.z};
        float pz[4] = {a.z, bb.y, cc.x, cc.w};
        float rr[4] = {r4.x, r4.y, r4.z, r4.w};
#pragma unroll
        for (int j = 0; j < 4; ++j) {
          float dx = px[j] - pm.x, dy = py[j] - pm.y, dz = pz[j] - pm.z;
          float d2 = __builtin_fmaf(dx, dx, __builtin_fmaf(dy, dy, dz * dz));
          part = __builtin_fmaf(fast_exp2(nc * d2), rr[j], part);
        }
      }
    }
  }
  part += __shfl_xor(part, 1, 64);
  part += __shfl_xor(part, 2, 64);
  part += __shfl_xor(part, 4, 64);
  part += __shfl_xor(part, 8, 64);
  if (c == 0) {
    float t1v = part;
    float rr = sRR[m_idx];
    float colsum = rr * t1v;
    float cs = fminf(rr / (colsum + 1e-9f), 1.0f);
    float ccv = rr * cs;
    float rn = fmaxf(rr - colsum * cs, 0.f);
    cohStore(wpB + t0 + m_idx, packh2(ccv, rn));
    sRR[m_idx] = rn;
  }
}

__global__ __launch_bounds__(BLOCK, 4) void emd_fused_kernel(
    const float* __restrict__ xyz1, const float* __restrict__ xyz2,
    float* __restrict__ out, float* __restrict__ rowscaleG,
    float* __restrict__ wPack, float* __restrict__ R9acc,
    float* __restrict__ t9, float* __restrict__ outAcc,
    unsigned* __restrict__ ctr) {
  __shared__ float4 sP[MPTS];              // raw x2,y2,z2; w = level payload
  __shared__ float4 sStage[4 * 16 * SROW]; // sweep2T quad buffer
  __shared__ float sRedS[ROWS * 4];
  __shared__ float sRedC[ROWS * 4];
  __shared__ float sRedR[ROWS * 4];
  __shared__ float sCost[ROWS];
  __shared__ float sRowScale[ROWS];        // persistent across levels
  __shared__ float sRemainL[ROWS];         // persistent across levels
  __shared__ float sRR[ROWS];              // owner's rr slice, full precision

  const int tid = threadIdx.x;
  const int bid = blockIdx.x;
  const int b = bid >> 5;
  const int t0 = (bid & 31) * ROWS;
  const bool desig = (bid & 31) == 0;
  const int wave = tid >> 6, lane = tid & 63;
  const int mq = wave & 3;                 // m-quadrant
  const int rh = wave >> 2;                // row-quarter (0..3)
  const size_t bM = (size_t)b * MPTS;
  float costAcc = 0.f;                     // meaningful on tid==0

  float* rsG = rowscaleG + (size_t)b * NPTS;
  float* wpB = wPack + bM;
  const float4* q1 = (const float4*)(xyz1 + (size_t)b * NPTS * 3);
  const float4* q2 = (const float4*)(xyz2 + bM * 3);
#define CTRB(s) (ctr + (size_t)(((s) * BATCH + b) * NSUB) * PAD)

  // ---- init: stage raw xyz2; rr_0 = 1; zero scalar accumulators ----
  if (tid < MPTS / 4) {
    int g = tid;
    float4 a = q2[3 * g], bb = q2[3 * g + 1], c = q2[3 * g + 2];
    sP[4 * g + 0] = make_float4(a.x, a.y, a.z, 0.f);
    sP[4 * g + 1] = make_float4(a.w, bb.x, bb.y, 0.f);
    sP[4 * g + 2] = make_float4(bb.z, bb.w, c.x, 0.f);
    sP[4 * g + 3] = make_float4(c.y, c.z, c.w, 0.f);
  }
  if (tid < ROWS) sRR[tid] = 1.0f;
  if (desig && tid == 0) {
    cohStore(R9acc + b * PAD, 0.f);
    cohStore(t9 + b * PAD, 0.f);
    cohStore(outAcc + b * PAD, 0.f);
  }
  __syncthreads();

  // ---- A0: rowscale_0 ----
  const float nc0 = -16384.0f * LOG2E;
  {
    const int ph = lane >> 1, rg = lane & 1;
    float x1a[8], y1a[8], z1a[8], acc[8];
    load8(q1, t0 + rh * 16 + rg * 8, x1a, y1a, z1a);
#pragma unroll
    for (int j = 0; j < 8; ++j) acc[j] = 0.f;
    const int mb = mq * 512 + ph;
#pragma unroll 2
    for (int it = 0; it < 16; ++it) {
      float4 v = sP[mb + it * 32];
#pragma unroll
      for (int j = 0; j < 8; ++j) {
        float dx = x1a[j] - v.x, dy = y1a[j] - v.y, dz = z1a[j] - v.z;
        float d2 = __builtin_fmaf(dx, dx, __builtin_fmaf(dy, dy, dz * dz));
        acc[j] += fast_exp2(nc0 * d2);
      }
    }
#pragma unroll
    for (int j = 0; j < 8; ++j) {
      acc[j] += __shfl_xor(acc[j], 2, 64);
      acc[j] += __shfl_xor(acc[j], 4, 64);
      acc[j] += __shfl_xor(acc[j], 8, 64);
      acc[j] += __shfl_xor(acc[j], 16, 64);
      acc[j] += __shfl_xor(acc[j], 32, 64);
    }
    if (lane < 2) {
#pragma unroll
      for (int j = 0; j < 8; ++j)
        sRedS[(rh * 16 + rg * 8 + j) * 4 + mq] = acc[j];
    }
    __syncthreads();
    if (tid < ROWS) {
      float s = sRedS[tid * 4] + sRedS[tid * 4 + 1] + sRedS[tid * 4 + 2] +
                sRedS[tid * 4 + 3];
      float rs = 1.0f / (s + 1e-9f);
      sRowScale[tid] = rs;
      cohStore(rsG + t0 + tid, rs);
    }
  }
  batch_barrier(CTRB(0), bid);          // rs_0 + init zeroes visible
  sweep2T_fuse(nc0, tid, t0, q1, rsG, wpB, sP, sStage, sRR);   // -> wPack_0
  batch_barrier(CTRB(1), bid);          // wPack_0 visible

  // ---- persistent CA row fragment (raw coords) ----
  float x1[4], y1[4], z1[4];
  {
    int b4 = ((t0 + rh * 16 + (lane & 3) * 4) >> 2) * 3;
    float4 a = q1[b4], bb = q1[b4 + 1], c = q1[b4 + 2];
    x1[0] = a.x;  y1[0] = a.y;  z1[0] = a.z;
    x1[1] = a.w;  y1[1] = bb.x; z1[1] = bb.y;
    x1[2] = bb.z; y1[2] = bb.w; z1[2] = c.x;
    x1[3] = c.y;  y1[3] = c.z;  z1[3] = c.w;
  }
  const int phc = lane >> 2, rgc = lane & 3;
  const int mbc = mq * 512 + phc;

  float nc2 = -4096.0f * LOG2E;   // levels[l+1]*LOG2E; exact /4 per level
  for (int l = 0; l < 9; ++l) {
    const bool LAST = (l == 8);
    // -- staging: sP[m].w = wPack_l[m], m = tid + 1024k --
#pragma unroll
    for (int k = 0; k < 2; ++k) {
      int m = tid + k * 1024;
      sP[m].w = cohLoad(wpB + m);
    }
    __syncthreads();
    // -- sweep1: cost(l) + remainL + rowscale(l+1). e1 = e2^4 (exact). --
    float accS[4] = {0.f, 0.f, 0.f, 0.f};
    float accC[4] = {0.f, 0.f, 0.f, 0.f};
    float accR[4] = {0.f, 0.f, 0.f, 0.f};
#pragma unroll 4
    for (int it = 0; it < 32; ++it) {
      float4 v = sP[mbc + it * 16];
      __half2 h = __builtin_bit_cast(__half2, v.w);
      float cc = __low2float(h);
      float rr = __high2float(h);
#pragma unroll
      for (int j = 0; j < 4; ++j) {
        float dx = x1[j] - v.x, dy = y1[j] - v.y, dz = z1[j] - v.z;
        float d2 = __builtin_fmaf(dx, dx, __builtin_fmaf(dy, dy, dz * dz));
        float sq = fast_sqrt(d2);
        float e2 = fast_exp2(nc2 * d2);
        float e2s = e2 * e2;
        float e1 = e2s * e2s;   // exp(levels[l]*d2); at LAST -> exp(-0.25 d2)
        float t = e1 * cc;
        accS[j] += t;
        accC[j] = __builtin_fmaf(t, sq, accC[j]);
        accR[j] = __builtin_fmaf(e2, rr, accR[j]);
      }
    }
#pragma unroll
    for (int j = 0; j < 4; ++j) {
      accS[j] += __shfl_xor(accS[j], 4, 64);
      accS[j] += __shfl_xor(accS[j], 8, 64);
      accS[j] += __shfl_xor(accS[j], 16, 64);
      accS[j] += __shfl_xor(accS[j], 32, 64);
      accC[j] += __shfl_xor(accC[j], 4, 64);
      accC[j] += __shfl_xor(accC[j], 8, 64);
      accC[j] += __shfl_xor(accC[j], 16, 64);
      accC[j] += __shfl_xor(accC[j], 32, 64);
      accR[j] += __shfl_xor(accR[j], 4, 64);
      accR[j] += __shfl_xor(accR[j], 8, 64);
      accR[j] += __shfl_xor(accR[j], 16, 64);
      accR[j] += __shfl_xor(accR[j], 32, 64);
    }
    if (lane < 4) {
#pragma unroll
      for (int j = 0; j < 4; ++j) {
        int row = rh * 16 + rgc * 4 + j;   // rgc == lane here
        sRedS[row * 4 + mq] = accS[j];
        sRedC[row * 4 + mq] = accC[j];
        sRedR[row * 4 + mq] = accR[j];
      }
    }
    __syncthreads();
    if (tid < ROWS) {
      float S2 = sRedS[tid * 4] + sRedS[tid * 4 + 1] + sRedS[tid * 4 + 2] +
                 sRedS[tid * 4 + 3];
      float C = sRedC[tid * 4] + sRedC[tid * 4 + 1] + sRedC[tid * 4 + 2] +
                sRedC[tid * 4 + 3];
      float R = sRedR[tid * 4] + sRedR[tid * 4 + 1] + sRedR[tid * 4 + 2] +
                sRedR[tid * 4 + 3];
      if (LAST) R = cohLoad(R9acc + b * PAD);   // sum_m rr_9 (e == 1)
      float rs = sRowScale[tid];
      float rl = (l == 0) ? 1.0f : sRemainL[tid];
      float rlN = fmaxf(rl - rs * S2, 0.f);
      sRemainL[tid] = rlN;
      float rsN = rlN / (R + 1e-9f);
      sRowScale[tid] = rsN;
      if (!LAST) cohStore(rsG + t0 + tid, rsN);
      sCost[tid] = rs * C;
    }
    __syncthreads();
    if (tid == 0) {
      float t = 0.f;
#pragma unroll
      for (int i = 0; i < ROWS; ++i) t += sCost[i];
      costAcc += t;
      if (LAST) {
        float r = 0.f;
#pragma unroll
        for (int i = 0; i < ROWS; ++i) r += sRowScale[i];
        atomicAdd(t9 + b * PAD, r);       // one per block, padded line
      }
    }
    if (!LAST) {
      batch_barrier(CTRB(2 + 2 * l), bid);    // rsN_{l+1} visible
      sweep2T_fuse(nc2, tid, t0, q1, rsG, wpB, sP, sStage, sRR);
      if (l == 7) {          // R9 = sum_m rr_9: block partial, one atomic
        __syncthreads();
        if (tid == 0) {
          float r9 = 0.f;
#pragma unroll
          for (int i = 0; i < ROWS; ++i) r9 += sRR[i];
          atomicAdd(R9acc + b * PAD, r9);
        }
      }
      batch_barrier(CTRB(3 + 2 * l), bid);    // wPack_{l+1} (+R9acc) visible
      nc2 *= 0.25f;
    }
  }
  batch_barrier(CTRB(18), bid);               // t9 complete

  // ---- C9 owner publish: w[m] from full-precision rr_9 + t9 ----
  if (tid < ROWS) {
    float rr = sRR[tid];
    float t1s = cohLoad(t9 + b * PAD);
    float w = rr * fminf(rr / (__builtin_fmaf(rr, t1s, 1e-9f)), 1.0f);
    cohStore(wpB + t0 + tid, w);              // full float (matches old C9)
  }
  batch_barrier(CTRB(19), bid);               // w visible

  // ---- C9 (lvl=0): cost with unscaled coords ----
  {
#pragma unroll
    for (int k = 0; k < 2; ++k) {
      int m = tid + k * 1024;
      sP[m].w = cohLoad(wpB + m);
    }
    __syncthreads();
    const int ph = lane >> 1, rg = lane & 1;
    float x1a[8], y1a[8], z1a[8], acc[8];
    load8(q1, t0 + rh * 16 + rg * 8, x1a, y1a, z1a);
#pragma unroll
    for (int j = 0; j < 8; ++j) acc[j] = 0.f;
    const int mb = mq * 512 + ph;
#pragma unroll 2
    for (int it = 0; it < 16; ++it) {
      float4 v = sP[mb + it * 32];
#pragma unroll
      for (int j = 0; j < 8; ++j) {
        float dx = x1a[j] - v.x, dy = y1a[j] - v.y, dz = z1a[j] - v.z;
        float d2 = __builtin_fmaf(dx, dx, __builtin_fmaf(dy, dy, dz * dz));
        acc[j] = __builtin_fmaf(fast_sqrt(d2), v.w, acc[j]);
      }
    }
#pragma unroll
    for (int j = 0; j < 8; ++j) {
      acc[j] += __shfl_xor(acc[j], 2, 64);
      acc[j] += __shfl_xor(acc[j], 4, 64);
      acc[j] += __shfl_xor(acc[j], 8, 64);
      acc[j] += __shfl_xor(acc[j], 16, 64);
      acc[j] += __shfl_xor(acc[j], 32, 64);
    }
    if (lane < 2) {
#pragma unroll
      for (int j = 0; j < 8; ++j)
        sRedS[(rh * 16 + rg * 8 + j) * 4 + mq] = acc[j];
    }
    __syncthreads();
    if (tid < ROWS) {
      float C = sRedS[tid * 4] + sRedS[tid * 4 + 1] + sRedS[tid * 4 + 2] +
                sRedS[tid * 4 + 3];
      sCost[tid] = sRowScale[tid] * C;
    }
    __syncthreads();
    if (tid == 0) {
      float t = 0.f;
#pragma unroll
      for (int i = 0; i < ROWS; ++i) t += sCost[i];
      costAcc += t;
      atomicAdd(outAcc + b * PAD, costAcc);   // ONE atomic per block total
    }
  }
  batch_barrier(CTRB(20), bid);               // outAcc complete
  if (desig && tid == 0) out[b] = cohLoad(outAcc + b * PAD);
#undef CTRB
}

// ---------------------------------------------------------------------------
extern "C" void kernel_launch(void* const* d_in, const int* in_sizes, int n_in,
                              void* d_out, int out_size, void* d_ws, size_t ws_size,
                              hipStream_t stream) {
  const float* xyz1 = (const float*)d_in[0];
  const float* xyz2 = (const float*)d_in[1];
  float* out = (float*)d_out;
  float* ws = (float*)d_ws;

  const int BM = BATCH * MPTS;               // 16384
  float* rowscaleG = ws;                     // BM
  float* wPack     = ws + BM;                // BM
  float* R9acc     = ws + 2 * BM;            // BATCH*PAD
  float* t9        = ws + 2 * BM + BATCH * PAD;      // BATCH*PAD
  float* outAcc    = ws + 2 * BM + 2 * BATCH * PAD;  // BATCH*PAD
  unsigned* ctr    = (unsigned*)(ws + 2 * BM + 3 * BATCH * PAD);
  // ctr: NSYNC*BATCH*NSUB*PAD u32 = 21*8*8*16 = 21504 u32 (~86KB)

  hipMemsetAsync(ctr, 0, (size_t)NSYNC * BATCH * NSUB * PAD * sizeof(unsigned),
                 stream);

  void* args[] = {(void*)&xyz1, (void*)&xyz2, (void*)&out, (void*)&rowscaleG,
                  (void*)&wPack, (void*)&R9acc, (void*)&t9, (void*)&outAcc,
                  (void*)&ctr};
  hipLaunchKernel((const void*)emd_fused_kernel,
                  dim3(BATCH * (NPTS / ROWS)), dim3(BLOCK), args, 0, stream);
}